// Round 1
// baseline (1215.089 us; speedup 1.0000x reference)
//
#include <hip/hip_runtime.h>
#include <cstdint>
#include <cstddef>

#define Bsz 32
#define C1 128
#define C2 256
#define Hh 56
#define Wd 56
#define HW 3136                  // 56*56
#define NHW 100352               // 32*3136
#define N1 ((size_t)12845056)    // 32*128*3136
#define N2 ((size_t)25690112)    // 32*256*3136

// ---- workspace layout (bytes) ----
// q2  : [0, N1)
// q1  : [N1, 2*N1)
// acc1: [2*N1, 2*N1+4*N1)          (dead after quant1)
// acc2: [2*N1, 2*N1+4*N2)          (overlays acc1+q1, both dead by conv2)
// q3  : [2*N1+4*N2, +N2)
// stats after that (8-aligned)
static constexpr size_t OFF_Q2 = 0;
static constexpr size_t OFF_Q1 = N1;
static constexpr size_t OFF_ACC1 = 2 * N1;
static constexpr size_t OFF_ACC2 = 2 * N1;
static constexpr size_t OFF_Q3 = 2 * N1 + 4 * N2;
static constexpr size_t OFF_STATS = OFF_Q3 + N2;

struct Stats {
  int absmax1, absmax2, pad0, pad1;
  float scale1, e1, s2, e2;
  float scaleq2, e3, sf, ef;
  long long sum1[C1];
  unsigned long long sumsq1[C1];
  int min1[C1], max1[C1];
  float A1[C1], B1c[C1];
  long long sum2[C2];
  unsigned long long sumsq2[C2];
  int min2[C2], max2[C2];
  float A2[C2], B2c[C2];
};

__global__ void k_init(Stats* st) {
  int t = threadIdx.x;
  if (t == 0) { st->absmax1 = 0; st->absmax2 = 0; }
  for (int c = t; c < C1; c += 256) {
    st->sum1[c] = 0; st->sumsq1[c] = 0; st->min1[c] = 127; st->max1[c] = -128;
  }
  for (int c = t; c < C2; c += 256) {
    st->sum2[c] = 0; st->sumsq2[c] = 0; st->min2[c] = 127; st->max2[c] = -128;
  }
}

// 3x3 dense conv, 128->128, pad 1. Block: one (n,h), 64 co, all 56 w.
__global__ __launch_bounds__(256) void k_conv1(
    const int* __restrict__ x, const float* __restrict__ wDW,
    int* __restrict__ acc1, int* __restrict__ absmax_p) {
  __shared__ float xs[16][3][58];
  __shared__ float wsm[64][145];   // 144 used, +1 pad breaks 8-way bank conflict
  __shared__ int reda[4];
  int t = threadIdx.x;
  int coB = blockIdx.x * 64;       // 0 or 64
  int h = blockIdx.y, n = blockIdx.z;
  int tx = t & 7, ty = t >> 3;
  int w0 = tx * 7;
  float acc[2][7];
#pragma unroll
  for (int a = 0; a < 2; a++)
#pragma unroll
    for (int j = 0; j < 7; j++) acc[a][j] = 0.f;

  for (int ci0 = 0; ci0 < C1; ci0 += 16) {
    for (int idx = t; idx < 16 * 3 * 58; idx += 256) {
      int ci = idx / 174, r = idx % 174, kh = r / 58, wx = r % 58;
      int hh = h - 1 + kh, ww = wx - 1;
      float v = 0.f;
      if (hh >= 0 && hh < Hh && ww >= 0 && ww < Wd)
        v = (float)x[(((size_t)n * C1 + ci0 + ci) * Hh + hh) * Wd + ww];
      xs[ci][kh][wx] = v;
    }
    for (int idx = t; idx < 64 * 144; idx += 256) {
      int co = idx / 144, k = idx % 144;
      wsm[co][k] = wDW[((size_t)(coB + co) * C1 + (ci0 + k / 9)) * 9 + (k % 9)];
    }
    __syncthreads();
    for (int ci = 0; ci < 16; ci++) {
#pragma unroll
      for (int kh = 0; kh < 3; kh++) {
        float xr[9];
#pragma unroll
        for (int j = 0; j < 9; j++) xr[j] = xs[ci][kh][w0 + j];
#pragma unroll
        for (int c2 = 0; c2 < 2; c2++) {
#pragma unroll
          for (int kw = 0; kw < 3; kw++) {
            float wv = wsm[ty * 2 + c2][ci * 9 + kh * 3 + kw];
#pragma unroll
            for (int j = 0; j < 7; j++)
              acc[c2][j] = fmaf(xr[j + kw], wv, acc[c2][j]);
          }
        }
      }
    }
    __syncthreads();
  }
  int am = 0;
#pragma unroll
  for (int c2 = 0; c2 < 2; c2++) {
    int co = coB + ty * 2 + c2;
    int* ob = acc1 + (((size_t)n * C1 + co) * Hh + h) * Wd + w0;
#pragma unroll
    for (int j = 0; j < 7; j++) {
      int v = __float2int_rn(acc[c2][j]);
      ob[j] = v;
      am = max(am, abs(v));
    }
  }
  for (int off = 32; off; off >>= 1) am = max(am, __shfl_down(am, off, 64));
  if ((t & 63) == 0) reda[t >> 6] = am;
  __syncthreads();
  if (t == 0) atomicMax(absmax_p, max(max(reda[0], reda[1]), max(reda[2], reda[3])));
}

// exact integer ceil(log2(v)); shift = max(bw-7,0); e_out = ea+eb+shift
__global__ void k_scale(const int* __restrict__ absmax_p,
                        const float* __restrict__ ea, const float* __restrict__ eb,
                        float* scale_out, float* e_out) {
  int v = *absmax_p;
  int p = 31 - __clz(v | 1);
  int bw = ((v & (v - 1)) == 0) ? p : p + 1;
  int shift = bw - 7; if (shift < 0) shift = 0;
  *scale_out = exp2f((float)(-shift));
  *e_out = *ea + *eb + (float)shift;
}

// quantize acc -> int8 (+ per-channel sum/sumsq/min/max). One block per (c,n).
__global__ __launch_bounds__(256) void k_quant_stats(
    const int* __restrict__ acc, signed char* __restrict__ q,
    const float* __restrict__ scale_p, long long* sums,
    unsigned long long* sumsqs, int* mins, int* maxs, int C) {
  int c = blockIdx.x, n = blockIdx.y, t = threadIdx.x;
  float scale = *scale_p;
  size_t base = ((size_t)n * C + c) * (size_t)HW;
  int s = 0, sq = 0, mn = 127, mx = -128;
  for (int i = t; i < HW; i += 256) {
    float r = rintf((float)acc[base + i] * scale);
    r = fminf(fmaxf(r, -128.f), 127.f);
    int qi = (int)r;
    q[base + i] = (signed char)qi;
    s += qi; sq += qi * qi; mn = min(mn, qi); mx = max(mx, qi);
  }
  for (int off = 32; off; off >>= 1) {
    s  += __shfl_down(s, off, 64);
    sq += __shfl_down(sq, off, 64);
    mn = min(mn, __shfl_down(mn, off, 64));
    mx = max(mx, __shfl_down(mx, off, 64));
  }
  __shared__ int rs[4], rsq[4], rmn[4], rmx[4];
  int wave = t >> 6, lane = t & 63;
  if (lane == 0) { rs[wave] = s; rsq[wave] = sq; rmn[wave] = mn; rmx[wave] = mx; }
  __syncthreads();
  if (t == 0) {
    s = rs[0] + rs[1] + rs[2] + rs[3];
    sq = rsq[0] + rsq[1] + rsq[2] + rsq[3];
    mn = min(min(rmn[0], rmn[1]), min(rmn[2], rmn[3]));
    mx = max(max(rmx[0], rmx[1]), max(rmx[2], rmx[3]));
    atomicAdd((unsigned long long*)&sums[c], (unsigned long long)(long long)s);
    atomicAdd(&sumsqs[c], (unsigned long long)(unsigned)sq);
    atomicMin(&mins[c], mn);
    atomicMax(&maxs[c], mx);
  }
}

// per-channel bn affine y = A*q + B; global rng from channel min/max extremes;
// s_out = 2^(7-bw), e_out = bw-7. blockDim == C.
__global__ void k_bn(const long long* __restrict__ sums,
                     const unsigned long long* __restrict__ sumsqs,
                     const int* __restrict__ mins, const int* __restrict__ maxs,
                     const float* __restrict__ gamma, const float* __restrict__ beta,
                     const float* __restrict__ e_in,
                     float* A, float* Bc, float* s_out, float* e_out,
                     float* e_extra, int C) {
  __shared__ float red[4];
  int t = threadIdx.x;
  float e1 = *e_in;
  double meanq = (double)sums[t] / (double)NHW;
  double varq = (double)sumsqs[t] / (double)NHW - meanq * meanq;
  float se = exp2f(e1);
  float mean = (float)meanq * se;
  float var = (float)varq * se * se;
  float rsq = 1.0f / sqrtf(var + 1e-5f);
  float g = gamma[t], b = beta[t];
  float Av = g * se * rsq;
  float Bv = b - g * mean * rsq;
  A[t] = Av; Bc[t] = Bv;
  float cand = fmaxf(fabsf(Av * (float)mins[t] + Bv), fabsf(Av * (float)maxs[t] + Bv));
  for (int off = 32; off; off >>= 1) cand = fmaxf(cand, __shfl_down(cand, off, 64));
  int wave = t >> 6, lane = t & 63;
  if (lane == 0) red[wave] = cand;
  __syncthreads();
  if (t == 0) {
    float rng = red[0];
    for (int i = 1; i < C / 64; i++) rng = fmaxf(rng, red[i]);
    float bwv = ceilf(log2f(rng));
    *s_out = exp2f(7.0f - bwv);
    *e_out = bwv - 7.0f;
    if (e_extra) *e_extra = bwv - 7.0f;
  }
}

// q2 = relu(clip(round((A*q1+B) * s2)))
__global__ __launch_bounds__(256) void k_q2(
    const signed char* __restrict__ q1, signed char* __restrict__ q2,
    const Stats* __restrict__ st) {
  unsigned i = blockIdx.x * 256u + threadIdx.x;
  if (i >= (unsigned)N1) return;
  unsigned c = (i / HW) & (C1 - 1);
  float y = st->A1[c] * (float)q1[i] + st->B1c[c];
  float r = rintf(y * st->s2);
  r = fminf(fmaxf(r, -128.f), 127.f);
  r = fmaxf(r, 0.f);
  q2[i] = (signed char)r;
}

// 1x1 conv 128->256 as GEMM. Block: 256 hw x 64 co, one n.
__global__ __launch_bounds__(256) void k_conv2(
    const signed char* __restrict__ q2, const float* __restrict__ wPW,
    int* __restrict__ acc2, int* __restrict__ absmax_p) {
  __shared__ float wt[64][128];
  __shared__ int reda[4];
  int t = threadIdx.x;
  int n = blockIdx.z, co0 = blockIdx.y * 64, hw0 = blockIdx.x * 256;
  for (int idx = t; idx < 8192; idx += 256)
    wt[idx >> 7][idx & 127] = wPW[(size_t)(co0 + (idx >> 7)) * C1 + (idx & 127)];
  __syncthreads();
  int hw = hw0 + t;
  bool valid = hw < HW;
  float acc[64];
#pragma unroll
  for (int i = 0; i < 64; i++) acc[i] = 0.f;
  const signed char* xb = q2 + (size_t)n * C1 * HW + (valid ? hw : 0);
  for (int ci0 = 0; ci0 < C1; ci0 += 16) {
    float xv[16];
#pragma unroll
    for (int j = 0; j < 16; j++)
      xv[j] = valid ? (float)xb[(size_t)(ci0 + j) * HW] : 0.f;
#pragma unroll
    for (int co = 0; co < 64; co++) {
      const float4* wr = (const float4*)&wt[co][ci0];
#pragma unroll
      for (int jj = 0; jj < 4; jj++) {
        float4 wv = wr[jj];
        acc[co] = fmaf(xv[jj * 4 + 0], wv.x, acc[co]);
        acc[co] = fmaf(xv[jj * 4 + 1], wv.y, acc[co]);
        acc[co] = fmaf(xv[jj * 4 + 2], wv.z, acc[co]);
        acc[co] = fmaf(xv[jj * 4 + 3], wv.w, acc[co]);
      }
    }
  }
  int am = 0;
  if (valid) {
    int* ob = acc2 + ((size_t)n * C2 + co0) * (size_t)HW + hw;
#pragma unroll
    for (int co = 0; co < 64; co++) {
      int v = __float2int_rn(acc[co]);
      ob[(size_t)co * HW] = v;
      am = max(am, abs(v));
    }
  }
  for (int off = 32; off; off >>= 1) am = max(am, __shfl_down(am, off, 64));
  if ((t & 63) == 0) reda[t >> 6] = am;
  __syncthreads();
  if (t == 0) atomicMax(absmax_p, max(max(reda[0], reda[1]), max(reda[2], reda[3])));
}

// final: out = relu(clip(round((A2*q3+B2)*sf))) as float
__global__ __launch_bounds__(256) void k_out(
    const signed char* __restrict__ q3, const Stats* __restrict__ st,
    float* __restrict__ out) {
  unsigned i = blockIdx.x * 256u + threadIdx.x;
  if (i >= (unsigned)N2) return;
  unsigned c = (i / HW) & (C2 - 1);
  float y = st->A2[c] * (float)q3[i] + st->B2c[c];
  float r = rintf(y * st->sf);
  r = fminf(fmaxf(r, -128.f), 127.f);
  r = fmaxf(r, 0.f);
  out[i] = r;
}

extern "C" void kernel_launch(void* const* d_in, const int* in_sizes, int n_in,
                              void* d_out, int out_size, void* d_ws, size_t ws_size,
                              hipStream_t stream) {
  const int* x = (const int*)d_in[0];
  const float* x_exp = (const float*)d_in[1];
  const float* wDW = (const float*)d_in[2];
  const float* wDW_exp = (const float*)d_in[3];
  const float* wPW = (const float*)d_in[4];
  const float* wPW_exp = (const float*)d_in[5];
  const float* gamma1 = (const float*)d_in[6];
  const float* beta1 = (const float*)d_in[7];
  const float* gamma2 = (const float*)d_in[8];
  const float* beta2 = (const float*)d_in[9];
  float* out = (float*)d_out;

  char* ws = (char*)d_ws;
  signed char* q2 = (signed char*)(ws + OFF_Q2);
  signed char* q1 = (signed char*)(ws + OFF_Q1);
  int* acc1 = (int*)(ws + OFF_ACC1);
  int* acc2 = (int*)(ws + OFF_ACC2);
  signed char* q3 = (signed char*)(ws + OFF_Q3);
  Stats* st = (Stats*)(ws + OFF_STATS);

  hipLaunchKernelGGL(k_init, dim3(1), dim3(256), 0, stream, st);

  hipLaunchKernelGGL(k_conv1, dim3(2, 56, 32), dim3(256), 0, stream,
                     x, wDW, acc1, &st->absmax1);
  hipLaunchKernelGGL(k_scale, dim3(1), dim3(1), 0, stream,
                     &st->absmax1, x_exp, wDW_exp, &st->scale1, &st->e1);
  hipLaunchKernelGGL(k_quant_stats, dim3(C1, Bsz), dim3(256), 0, stream,
                     acc1, q1, &st->scale1, st->sum1, st->sumsq1, st->min1, st->max1, C1);
  hipLaunchKernelGGL(k_bn, dim3(1), dim3(C1), 0, stream,
                     st->sum1, st->sumsq1, st->min1, st->max1, gamma1, beta1,
                     &st->e1, st->A1, st->B1c, &st->s2, &st->e2, (float*)nullptr, C1);
  hipLaunchKernelGGL(k_q2, dim3((unsigned)(N1 / 256)), dim3(256), 0, stream,
                     q1, q2, st);

  hipLaunchKernelGGL(k_conv2, dim3(13, 4, 32), dim3(256), 0, stream,
                     q2, wPW, acc2, &st->absmax2);
  hipLaunchKernelGGL(k_scale, dim3(1), dim3(1), 0, stream,
                     &st->absmax2, &st->e2, wPW_exp, &st->scaleq2, &st->e3);
  hipLaunchKernelGGL(k_quant_stats, dim3(C2, Bsz), dim3(256), 0, stream,
                     acc2, q3, &st->scaleq2, st->sum2, st->sumsq2, st->min2, st->max2, C2);
  hipLaunchKernelGGL(k_bn, dim3(1), dim3(C2), 0, stream,
                     st->sum2, st->sumsq2, st->min2, st->max2, gamma2, beta2,
                     &st->e3, st->A2, st->B2c, &st->sf, &st->ef, out + N2, C2);
  hipLaunchKernelGGL(k_out, dim3((unsigned)(N2 / 256)), dim3(256), 0, stream,
                     q3, st, out);
}

// Round 2
// 427.513 us; speedup vs baseline: 2.8422x; 2.8422x over previous
//
#include <hip/hip_runtime.h>
#include <cstdint>
#include <cstddef>

#define Bsz 32
#define C1 128
#define C2 256
#define Hh 56
#define Wd 56
#define HW 3136                  // 56*56
#define NHW 100352               // 32*3136
#define N1 ((size_t)12845056)    // 32*128*3136
#define N2 ((size_t)25690112)    // 32*256*3136
#define XPSZ ((size_t)32 * 58 * 58 * 128)   // padded NHWC int8 input

typedef int v4i __attribute__((ext_vector_type(4)));
typedef int v16i __attribute__((ext_vector_type(16)));

// ---- workspace layout (bytes) ----
// q2t : [0, N1)              int8 [g][128]   (relu-quantized conv1 output)
// q1  : [N1, 2*N1)           int8 [g][128]   (dead after k_q2t; wq2 overlays at N1)
// acc1: [2*N1, 6*N1)         int32 [g][128]  (dead after qstats1)
// xp  : [6*N1, 6*N1+XPSZ)    int8 padded NHWC (dead after conv1)
// acc2: [2*N1, 2*N1+4*N2)    int32 [g][256]  (overlays acc1+xp, both dead)
// q3  : [2*N1+4*N2, +N2)     int8 [g][256]   (wq1 overlays start; dead by qstats2)
// stats after that
static constexpr size_t OFF_Q2T = 0;
static constexpr size_t OFF_Q1 = N1;
static constexpr size_t OFF_WQ2 = N1;            // overlays q1 (q1 dead first)
static constexpr size_t OFF_ACC1 = 2 * N1;
static constexpr size_t OFF_XP = 6 * N1;
static constexpr size_t OFF_ACC2 = 2 * N1;
static constexpr size_t OFF_Q3 = 2 * N1 + 4 * N2;
static constexpr size_t OFF_WQ1 = OFF_Q3;        // overlays q3 (wq1 dead before q3 written)
static constexpr size_t OFF_STATS = OFF_Q3 + N2;

struct Stats {
  int absmax1, absmax2, pad0, pad1;
  float scale1, e1, s2, e2;
  float scaleq2, e3, sf, ef;
  long long sum1[C1];
  unsigned long long sumsq1[C1];
  int min1[C1], max1[C1];
  float A1[C1], B1c[C1];
  long long sum2[C2];
  unsigned long long sumsq2[C2];
  int min2[C2], max2[C2];
  float A2[C2], B2c[C2];
};

__global__ void k_init(Stats* st) {
  int t = threadIdx.x;
  if (t == 0) { st->absmax1 = 0; st->absmax2 = 0; }
  for (int c = t; c < C1; c += 256) {
    st->sum1[c] = 0; st->sumsq1[c] = 0; st->min1[c] = 127; st->max1[c] = -128;
  }
  for (int c = t; c < C2; c += 256) {
    st->sum2[c] = 0; st->sumsq2[c] = 0; st->min2[c] = 127; st->max2[c] = -128;
  }
}

// x int32 NCHW -> xp int8 padded NHWC [n][hh][ww][ci], borders pre-zeroed by memset.
// One block per (h, n). LDS transpose: read coalesced NCHW, write coalesced NHWC.
__global__ __launch_bounds__(256) void k_prep_x(
    const int* __restrict__ x, signed char* __restrict__ xp) {
  __shared__ signed char lds[56 * 132];   // [w][128 + 4 pad] -> stride 33 words
  int t = threadIdx.x;
  int h = blockIdx.x;   // 0..55
  int n = blockIdx.y;
  const int* xb = x + (size_t)n * C1 * HW + h * 56;
  for (int idx = t; idx < 7168; idx += 256) {
    int c = idx / 56, w = idx - c * 56;
    lds[w * 132 + c] = (signed char)xb[(size_t)c * HW + w];
  }
  __syncthreads();
  int* xpw = (int*)(xp + (((size_t)n * 58 + h + 1) * 58 + 1) * 128);
  for (int idx = t; idx < 56 * 32; idx += 256) {
    int w = idx >> 5, c4 = idx & 31;
    xpw[w * 32 + c4] = *(const int*)(&lds[w * 132 + c4 * 4]);
  }
}

// wDW [co][ci][kh][kw] float -> wq1 int8 [co][pos*128+ci], pos = kh*3+kw
__global__ void k_prep_w1(const float* __restrict__ wDW, signed char* __restrict__ wq1) {
  int idx = blockIdx.x * 256 + threadIdx.x;
  if (idx >= 128 * 1152) return;
  int co = idx / 1152, r = idx - co * 1152;
  int ci = r / 9, pos = r - ci * 9;
  wq1[(size_t)co * 1152 + pos * 128 + ci] = (signed char)(int)wDW[idx];
}

// wPW [co][ci] float -> wq2 int8 [co][ci]
__global__ void k_prep_w2(const float* __restrict__ wPW, signed char* __restrict__ wq2) {
  int i = blockIdx.x * 256 + threadIdx.x;
  wq2[i] = (signed char)(int)wPW[i];
}

// 3x3 conv 128->128 as implicit GEMM with int8 MFMA.
// Block: 64 pixels x 128 co, one n. Wave (mw,nw): 32 pix x 64 co (2 MFMA tiles).
__global__ __launch_bounds__(256) void k_conv1m(
    const signed char* __restrict__ xp, const signed char* __restrict__ wq1,
    int* __restrict__ out, int* __restrict__ absmax_p) {
  __shared__ int reda[4];
  int t = threadIdx.x;
  int lane = t & 63, wave = t >> 6;
  int half = lane >> 5, l31 = lane & 31;
  int n = blockIdx.y;
  int p0 = blockIdx.x * 64;
  int mw = wave & 1, nw = wave >> 1;
  int m = p0 + mw * 32 + l31;
  int h = m / 56, w = m - h * 56;
  const signed char* abase0 = xp + (((size_t)n * 58 + h) * 58 + w) * 128 + half * 16;
  const signed char* bbase = wq1 + (size_t)(nw * 64 + l31) * 1152 + half * 16;
  v16i acc0, acc1;
#pragma unroll
  for (int r = 0; r < 16; ++r) { acc0[r] = 0; acc1[r] = 0; }
#pragma unroll
  for (int pos = 0; pos < 9; ++pos) {
    int kh = pos / 3, kw = pos % 3;
    const signed char* ab = abase0 + (kh * 58 + kw) * 128;
    const signed char* bb = bbase + pos * 128;
#pragma unroll
    for (int cb = 0; cb < 128; cb += 32) {
      v4i af = *(const v4i*)(ab + cb);
      v4i bf0 = *(const v4i*)(bb + cb);
      v4i bf1 = *(const v4i*)(bb + 32 * 1152 + cb);
      acc0 = __builtin_amdgcn_mfma_i32_32x32x32_i8(af, bf0, acc0, 0, 0, 0);
      acc1 = __builtin_amdgcn_mfma_i32_32x32x32_i8(af, bf1, acc1, 0, 0, 0);
    }
  }
  int am = 0;
  int* ob = out + ((size_t)n * HW + p0 + mw * 32) * 128 + nw * 64 + l31;
#pragma unroll
  for (int reg = 0; reg < 16; ++reg) {
    int row = (reg & 3) + 8 * (reg >> 2) + 4 * half;
    int v0 = acc0[reg], v1 = acc1[reg];
    ob[(size_t)row * 128] = v0;
    ob[(size_t)row * 128 + 32] = v1;
    am = max(am, max(abs(v0), abs(v1)));
  }
  for (int off = 32; off; off >>= 1) am = max(am, __shfl_down(am, off, 64));
  if (lane == 0) reda[wave] = am;
  __syncthreads();
  if (t == 0) atomicMax(absmax_p, max(max(reda[0], reda[1]), max(reda[2], reda[3])));
}

// 1x1 conv 128->256 as GEMM with int8 MFMA. Block: 64 pixels x 256 co.
// Wave (mw,nw): 32 pix x 128 co (4 MFMA tiles).
__global__ __launch_bounds__(256) void k_conv2m(
    const signed char* __restrict__ q2, const signed char* __restrict__ wq2,
    int* __restrict__ out, int* __restrict__ absmax_p) {
  __shared__ int reda[4];
  int t = threadIdx.x, lane = t & 63, wave = t >> 6;
  int half = lane >> 5, l31 = lane & 31;
  size_t g0 = (size_t)blockIdx.x * 64;
  int mw = wave & 1, nw = wave >> 1;
  size_t m = g0 + mw * 32 + l31;
  const signed char* ab = q2 + m * 128 + half * 16;
  const signed char* bb = wq2 + (size_t)(nw * 128 + l31) * 128 + half * 16;
  v16i acc[4];
#pragma unroll
  for (int ct = 0; ct < 4; ++ct)
#pragma unroll
    for (int r = 0; r < 16; ++r) acc[ct][r] = 0;
#pragma unroll
  for (int cb = 0; cb < 128; cb += 32) {
    v4i af = *(const v4i*)(ab + cb);
#pragma unroll
    for (int ct = 0; ct < 4; ++ct) {
      v4i bf = *(const v4i*)(bb + (size_t)ct * 32 * 128 + cb);
      acc[ct] = __builtin_amdgcn_mfma_i32_32x32x32_i8(af, bf, acc[ct], 0, 0, 0);
    }
  }
  int am = 0;
  int* ob = out + (g0 + mw * 32) * 256 + nw * 128 + l31;
#pragma unroll
  for (int ct = 0; ct < 4; ++ct) {
#pragma unroll
    for (int reg = 0; reg < 16; ++reg) {
      int row = (reg & 3) + 8 * (reg >> 2) + 4 * half;
      int v = acc[ct][reg];
      ob[(size_t)row * 256 + ct * 32] = v;
      am = max(am, abs(v));
    }
  }
  for (int off = 32; off; off >>= 1) am = max(am, __shfl_down(am, off, 64));
  if (lane == 0) reda[wave] = am;
  __syncthreads();
  if (t == 0) atomicMax(absmax_p, max(max(reda[0], reda[1]), max(reda[2], reda[3])));
}

// exact integer ceil(log2(v)); shift = max(bw-7,0); e_out = ea+eb+shift
__global__ void k_scale(const int* __restrict__ absmax_p,
                        const float* __restrict__ ea, const float* __restrict__ eb,
                        float* scale_out, float* e_out) {
  int v = *absmax_p;
  int p = 31 - __clz(v | 1);
  int bw = ((v & (v - 1)) == 0) ? p : p + 1;
  int shift = bw - 7; if (shift < 0) shift = 0;
  *scale_out = exp2f((float)(-shift));
  *e_out = *ea + *eb + (float)shift;
}

// quantize pixel-major acc [g][C] -> int8 q [g][C] + per-channel stats.
// Block: PT=112 pixels; each thread owns one channel (C=1<<Csh).
__global__ __launch_bounds__(256) void k_qstats_t(
    const int* __restrict__ acc, signed char* __restrict__ q,
    const float* __restrict__ scale_p, long long* sums,
    unsigned long long* sumsqs, int* mins, int* maxs, int Csh) {
  __shared__ int ls[256], lsq[256], lmn[256], lmx[256];
  int t = threadIdx.x;
  int C = 1 << Csh;
  size_t g0 = (size_t)blockIdx.x * 112;
  float scale = *scale_p;
  int c = t & (C - 1);
  int s = 0, sq = 0, mn = 127, mx = -128;
  for (int idx = t; idx < (112 << Csh); idx += 256) {
    int p = idx >> Csh;
    size_t a = ((g0 + p) << Csh) | (size_t)c;
    float r = rintf((float)acc[a] * scale);
    r = fminf(fmaxf(r, -128.f), 127.f);
    int qi = (int)r;
    q[a] = (signed char)qi;
    s += qi; sq += qi * qi; mn = min(mn, qi); mx = max(mx, qi);
  }
  ls[t] = s; lsq[t] = sq; lmn[t] = mn; lmx[t] = mx;
  __syncthreads();
  if (t < C) {
    for (int u = t + C; u < 256; u += C) {
      s += ls[u]; sq += lsq[u];
      mn = min(mn, lmn[u]); mx = max(mx, lmx[u]);
    }
    atomicAdd((unsigned long long*)&sums[c], (unsigned long long)(long long)s);
    atomicAdd(&sumsqs[c], (unsigned long long)(unsigned)sq);
    atomicMin(&mins[c], mn);
    atomicMax(&maxs[c], mx);
  }
}

// per-channel bn affine y = A*q + B; global rng from channel min/max extremes.
__global__ void k_bn(const long long* __restrict__ sums,
                     const unsigned long long* __restrict__ sumsqs,
                     const int* __restrict__ mins, const int* __restrict__ maxs,
                     const float* __restrict__ gamma, const float* __restrict__ beta,
                     const float* __restrict__ e_in,
                     float* A, float* Bc, float* s_out, float* e_out,
                     float* e_extra, int C) {
  __shared__ float red[4];
  int t = threadIdx.x;
  float e1 = *e_in;
  double meanq = (double)sums[t] / (double)NHW;
  double varq = (double)sumsqs[t] / (double)NHW - meanq * meanq;
  float se = exp2f(e1);
  float mean = (float)meanq * se;
  float var = (float)varq * se * se;
  float rsq = 1.0f / sqrtf(var + 1e-5f);
  float g = gamma[t], b = beta[t];
  float Av = g * se * rsq;
  float Bv = b - g * mean * rsq;
  A[t] = Av; Bc[t] = Bv;
  float cand = fmaxf(fabsf(Av * (float)mins[t] + Bv), fabsf(Av * (float)maxs[t] + Bv));
  for (int off = 32; off; off >>= 1) cand = fmaxf(cand, __shfl_down(cand, off, 64));
  int wave = t >> 6, lane = t & 63;
  if (lane == 0) red[wave] = cand;
  __syncthreads();
  if (t == 0) {
    float rng = red[0];
    for (int i = 1; i < C / 64; i++) rng = fmaxf(rng, red[i]);
    float bwv = ceilf(log2f(rng));
    *s_out = exp2f(7.0f - bwv);
    *e_out = bwv - 7.0f;
    if (e_extra) *e_extra = bwv - 7.0f;
  }
}

// q2t = relu(clip(round((A*q1+B)*s2))), pixel-major [g][128], 4 bytes/thread
__global__ __launch_bounds__(256) void k_q2t(
    const signed char* __restrict__ q1, signed char* __restrict__ q2,
    const Stats* __restrict__ st) {
  unsigned i = blockIdx.x * 256u + threadIdx.x;   // word index, N1/4 total
  int v = ((const int*)q1)[i];
  int c0 = (i << 2) & 127;
  float s2 = st->s2;
  int outv = 0;
#pragma unroll
  for (int j = 0; j < 4; ++j) {
    int b = (signed char)(v >> (8 * j));
    float y = st->A1[c0 + j] * (float)b + st->B1c[c0 + j];
    float r = rintf(y * s2);
    r = fminf(fmaxf(r, -128.f), 127.f);
    r = fmaxf(r, 0.f);
    outv |= ((int)r & 0xff) << (8 * j);
  }
  ((int*)q2)[i] = outv;
}

// final: q3 [g][256] -> out NCHW float. Thread = channel, 16 consecutive pixels.
__global__ __launch_bounds__(256) void k_out(
    const signed char* __restrict__ q3, const Stats* __restrict__ st,
    float* __restrict__ out) {
  int c = threadIdx.x;
  int g0 = blockIdx.x * 16;
  int n = g0 / HW, p0 = g0 - n * HW;
  float Av = st->A2[c], Bv = st->B2c[c], sf = st->sf;
  float* ob = out + ((size_t)n * C2 + c) * HW + p0;
  float vals[16];
#pragma unroll
  for (int j = 0; j < 16; ++j) {
    float y = Av * (float)q3[(size_t)(g0 + j) * 256 + c] + Bv;
    float r = rintf(y * sf);
    r = fminf(fmaxf(r, -128.f), 127.f);
    vals[j] = fmaxf(r, 0.f);
  }
#pragma unroll
  for (int j = 0; j < 4; ++j)
    *(float4*)(ob + j * 4) = make_float4(vals[j * 4], vals[j * 4 + 1],
                                         vals[j * 4 + 2], vals[j * 4 + 3]);
}

extern "C" void kernel_launch(void* const* d_in, const int* in_sizes, int n_in,
                              void* d_out, int out_size, void* d_ws, size_t ws_size,
                              hipStream_t stream) {
  const int* x = (const int*)d_in[0];
  const float* x_exp = (const float*)d_in[1];
  const float* wDW = (const float*)d_in[2];
  const float* wDW_exp = (const float*)d_in[3];
  const float* wPW = (const float*)d_in[4];
  const float* wPW_exp = (const float*)d_in[5];
  const float* gamma1 = (const float*)d_in[6];
  const float* beta1 = (const float*)d_in[7];
  const float* gamma2 = (const float*)d_in[8];
  const float* beta2 = (const float*)d_in[9];
  float* out = (float*)d_out;

  char* ws = (char*)d_ws;
  signed char* q2t = (signed char*)(ws + OFF_Q2T);
  signed char* q1 = (signed char*)(ws + OFF_Q1);
  signed char* wq2 = (signed char*)(ws + OFF_WQ2);
  int* acc1 = (int*)(ws + OFF_ACC1);
  signed char* xp = (signed char*)(ws + OFF_XP);
  int* acc2 = (int*)(ws + OFF_ACC2);
  signed char* q3 = (signed char*)(ws + OFF_Q3);
  signed char* wq1 = (signed char*)(ws + OFF_WQ1);
  Stats* st = (Stats*)(ws + OFF_STATS);

  hipMemsetAsync(xp, 0, XPSZ, stream);
  hipLaunchKernelGGL(k_init, dim3(1), dim3(256), 0, stream, st);
  hipLaunchKernelGGL(k_prep_x, dim3(56, 32), dim3(256), 0, stream, x, xp);
  hipLaunchKernelGGL(k_prep_w1, dim3(576), dim3(256), 0, stream, wDW, wq1);

  hipLaunchKernelGGL(k_conv1m, dim3(49, 32), dim3(256), 0, stream,
                     xp, wq1, acc1, &st->absmax1);
  hipLaunchKernelGGL(k_scale, dim3(1), dim3(1), 0, stream,
                     &st->absmax1, x_exp, wDW_exp, &st->scale1, &st->e1);
  hipLaunchKernelGGL(k_qstats_t, dim3(896), dim3(256), 0, stream,
                     acc1, q1, &st->scale1, st->sum1, st->sumsq1, st->min1, st->max1, 7);
  hipLaunchKernelGGL(k_bn, dim3(1), dim3(C1), 0, stream,
                     st->sum1, st->sumsq1, st->min1, st->max1, gamma1, beta1,
                     &st->e1, st->A1, st->B1c, &st->s2, &st->e2, (float*)nullptr, C1);
  hipLaunchKernelGGL(k_q2t, dim3(12544), dim3(256), 0, stream, q1, q2t, st);

  hipLaunchKernelGGL(k_prep_w2, dim3(128), dim3(256), 0, stream, wPW, wq2);
  hipLaunchKernelGGL(k_conv2m, dim3(1568), dim3(256), 0, stream,
                     q2t, wq2, acc2, &st->absmax2);
  hipLaunchKernelGGL(k_scale, dim3(1), dim3(1), 0, stream,
                     &st->absmax2, &st->e2, wPW_exp, &st->scaleq2, &st->e3);
  hipLaunchKernelGGL(k_qstats_t, dim3(896), dim3(256), 0, stream,
                     acc2, q3, &st->scaleq2, st->sum2, st->sumsq2, st->min2, st->max2, 8);
  hipLaunchKernelGGL(k_bn, dim3(1), dim3(C2), 0, stream,
                     st->sum2, st->sumsq2, st->min2, st->max2, gamma2, beta2,
                     &st->e3, st->A2, st->B2c, &st->sf, &st->ef, out + N2, C2);
  hipLaunchKernelGGL(k_out, dim3(6272), dim3(256), 0, stream, q3, st, out);
}

// Round 3
// 399.046 us; speedup vs baseline: 3.0450x; 1.0713x over previous
//
#include <hip/hip_runtime.h>
#include <cstdint>
#include <cstddef>

#define Bsz 32
#define C1 128
#define C2 256
#define Hh 56
#define Wd 56
#define HW 3136                  // 56*56
#define NHW 100352               // 32*3136
#define N1 ((size_t)12845056)    // 32*128*3136
#define N2 ((size_t)25690112)    // 32*256*3136
#define XPSZ ((size_t)32 * 58 * 58 * 128)   // padded NHWC int8 input

typedef int v4i __attribute__((ext_vector_type(4)));
typedef int v16i __attribute__((ext_vector_type(16)));

// ---- workspace layout (bytes) ----
static constexpr size_t OFF_Q2T = 0;
static constexpr size_t OFF_Q1 = N1;
static constexpr size_t OFF_WQ2 = N1;            // overlays q1 (q1 dead first)
static constexpr size_t OFF_ACC1 = 2 * N1;
static constexpr size_t OFF_XP = 6 * N1;
static constexpr size_t OFF_ACC2 = 2 * N1;
static constexpr size_t OFF_Q3 = 2 * N1 + 4 * N2;
static constexpr size_t OFF_WQ1 = OFF_Q3;        // overlays q3 (wq1 dead before q3 written)
static constexpr size_t OFF_STATS = OFF_Q3 + N2;

struct Stats {
  int absmax1, absmax2, pad0, pad1;
  float scale1, e1, s2, e2;
  float scaleq2, e3, sf, ef;
  long long sum1[C1];
  unsigned long long sumsq1[C1];
  int min1[C1], max1[C1];
  float A1[C1], B1c[C1];
  long long sum2[C2];
  unsigned long long sumsq2[C2];
  int min2[C2], max2[C2];
  float A2[C2], B2c[C2];
};

__global__ void k_init(Stats* st) {
  int t = threadIdx.x;
  if (t == 0) { st->absmax1 = 0; st->absmax2 = 0; }
  for (int c = t; c < C1; c += 256) {
    st->sum1[c] = 0; st->sumsq1[c] = 0; st->min1[c] = 127; st->max1[c] = -128;
  }
  for (int c = t; c < C2; c += 256) {
    st->sum2[c] = 0; st->sumsq2[c] = 0; st->min2[c] = 127; st->max2[c] = -128;
  }
}

// x int32 NCHW -> xp int8 padded NHWC [n][hh][ww][ci], borders pre-zeroed by memset.
__global__ __launch_bounds__(256) void k_prep_x(
    const int* __restrict__ x, signed char* __restrict__ xp) {
  __shared__ signed char lds[56 * 132];
  int t = threadIdx.x;
  int h = blockIdx.x;
  int n = blockIdx.y;
  const int* xb = x + (size_t)n * C1 * HW + h * 56;
  for (int idx = t; idx < 7168; idx += 256) {
    int c = idx / 56, w = idx - c * 56;
    lds[w * 132 + c] = (signed char)xb[(size_t)c * HW + w];
  }
  __syncthreads();
  int* xpw = (int*)(xp + (((size_t)n * 58 + h + 1) * 58 + 1) * 128);
  for (int idx = t; idx < 56 * 32; idx += 256) {
    int w = idx >> 5, c4 = idx & 31;
    xpw[w * 32 + c4] = *(const int*)(&lds[w * 132 + c4 * 4]);
  }
}

// wDW [co][ci][kh][kw] float -> wq1 int8 [co][pos*128+ci]
__global__ void k_prep_w1(const float* __restrict__ wDW, signed char* __restrict__ wq1) {
  int idx = blockIdx.x * 256 + threadIdx.x;
  if (idx >= 128 * 1152) return;
  int co = idx / 1152, r = idx - co * 1152;
  int ci = r / 9, pos = r - ci * 9;
  wq1[(size_t)co * 1152 + pos * 128 + ci] = (signed char)(int)wDW[idx];
}

// wPW [co][ci] float -> wq2 int8 [co][ci]
__global__ void k_prep_w2(const float* __restrict__ wPW, signed char* __restrict__ wq2) {
  int i = blockIdx.x * 256 + threadIdx.x;
  wq2[i] = (signed char)(int)wPW[i];
}

// 3x3 conv 128->128 implicit GEMM. Block: 128 pix x 128 co, 4 waves.
// Wave: 64 pix x 64 co = 2x2 MFMA subtiles -> 4 MFMAs per 4 loads per K-step.
__global__ __launch_bounds__(256, 3) void k_conv1m(
    const signed char* __restrict__ xp, const signed char* __restrict__ wq1,
    int* __restrict__ out, int* __restrict__ absmax_p) {
  __shared__ int reda[4];
  int t = threadIdx.x, lane = t & 63, wave = t >> 6;
  int half = lane >> 5, l31 = lane & 31;
  int mw = wave & 1, nw = wave >> 1;
  size_t g0 = (size_t)blockIdx.x * 128;

  const signed char* abase[2];
#pragma unroll
  for (int i = 0; i < 2; ++i) {
    size_t gm = g0 + mw * 64 + i * 32 + l31;
    int n = (int)(gm / HW);
    int p = (int)(gm - (size_t)n * HW);
    int h = p / 56, w = p - h * 56;
    abase[i] = xp + (((size_t)n * 58 + h) * 58 + w) * 128 + half * 16;
  }
  const signed char* bbase[2];
#pragma unroll
  for (int j = 0; j < 2; ++j)
    bbase[j] = wq1 + (size_t)(nw * 64 + j * 32 + l31) * 1152 + half * 16;

  v16i acc[2][2];
#pragma unroll
  for (int i = 0; i < 2; ++i)
#pragma unroll
    for (int j = 0; j < 2; ++j)
#pragma unroll
      for (int r = 0; r < 16; ++r) acc[i][j][r] = 0;

#pragma unroll
  for (int pos = 0; pos < 9; ++pos) {
    int kh = pos / 3, kw = pos - kh * 3;
    int aoff = (kh * 58 + kw) * 128;
    const signed char* a0 = abase[0] + aoff;
    const signed char* a1 = abase[1] + aoff;
    const signed char* b0 = bbase[0] + pos * 128;
    const signed char* b1 = bbase[1] + pos * 128;
#pragma unroll
    for (int cb = 0; cb < 128; cb += 32) {
      v4i af0 = *(const v4i*)(a0 + cb);
      v4i af1 = *(const v4i*)(a1 + cb);
      v4i bf0 = *(const v4i*)(b0 + cb);
      v4i bf1 = *(const v4i*)(b1 + cb);
      acc[0][0] = __builtin_amdgcn_mfma_i32_32x32x32_i8(af0, bf0, acc[0][0], 0, 0, 0);
      acc[0][1] = __builtin_amdgcn_mfma_i32_32x32x32_i8(af0, bf1, acc[0][1], 0, 0, 0);
      acc[1][0] = __builtin_amdgcn_mfma_i32_32x32x32_i8(af1, bf0, acc[1][0], 0, 0, 0);
      acc[1][1] = __builtin_amdgcn_mfma_i32_32x32x32_i8(af1, bf1, acc[1][1], 0, 0, 0);
    }
  }

  int am = 0;
#pragma unroll
  for (int i = 0; i < 2; ++i) {
#pragma unroll
    for (int reg = 0; reg < 16; ++reg) {
      int row = (reg & 3) + 8 * (reg >> 2) + 4 * half;
      int* ob = out + (g0 + mw * 64 + i * 32 + row) * 128 + nw * 64 + l31;
#pragma unroll
      for (int j = 0; j < 2; ++j) {
        int v = acc[i][j][reg];
        ob[j * 32] = v;
        am = max(am, abs(v));
      }
    }
  }
  for (int off = 32; off; off >>= 1) am = max(am, __shfl_down(am, off, 64));
  if (lane == 0) reda[wave] = am;
  __syncthreads();
  if (t == 0) atomicMax(absmax_p, max(max(reda[0], reda[1]), max(reda[2], reda[3])));
}

// 1x1 conv 128->256 GEMM. Block: 128 pix x 128 co (grid.y selects co half).
__global__ __launch_bounds__(256, 3) void k_conv2m(
    const signed char* __restrict__ q2, const signed char* __restrict__ wq2,
    int* __restrict__ out, int* __restrict__ absmax_p) {
  __shared__ int reda[4];
  int t = threadIdx.x, lane = t & 63, wave = t >> 6;
  int half = lane >> 5, l31 = lane & 31;
  int mw = wave & 1, nw = wave >> 1;
  size_t g0 = (size_t)blockIdx.x * 128;
  int co0 = blockIdx.y * 128;

  const signed char* ab[2];
#pragma unroll
  for (int i = 0; i < 2; ++i)
    ab[i] = q2 + (g0 + mw * 64 + i * 32 + l31) * 128 + half * 16;
  const signed char* bb[2];
#pragma unroll
  for (int j = 0; j < 2; ++j)
    bb[j] = wq2 + (size_t)(co0 + nw * 64 + j * 32 + l31) * 128 + half * 16;

  v16i acc[2][2];
#pragma unroll
  for (int i = 0; i < 2; ++i)
#pragma unroll
    for (int j = 0; j < 2; ++j)
#pragma unroll
      for (int r = 0; r < 16; ++r) acc[i][j][r] = 0;

#pragma unroll
  for (int cb = 0; cb < 128; cb += 32) {
    v4i af0 = *(const v4i*)(ab[0] + cb);
    v4i af1 = *(const v4i*)(ab[1] + cb);
    v4i bf0 = *(const v4i*)(bb[0] + cb);
    v4i bf1 = *(const v4i*)(bb[1] + cb);
    acc[0][0] = __builtin_amdgcn_mfma_i32_32x32x32_i8(af0, bf0, acc[0][0], 0, 0, 0);
    acc[0][1] = __builtin_amdgcn_mfma_i32_32x32x32_i8(af0, bf1, acc[0][1], 0, 0, 0);
    acc[1][0] = __builtin_amdgcn_mfma_i32_32x32x32_i8(af1, bf0, acc[1][0], 0, 0, 0);
    acc[1][1] = __builtin_amdgcn_mfma_i32_32x32x32_i8(af1, bf1, acc[1][1], 0, 0, 0);
  }

  int am = 0;
#pragma unroll
  for (int i = 0; i < 2; ++i) {
#pragma unroll
    for (int reg = 0; reg < 16; ++reg) {
      int row = (reg & 3) + 8 * (reg >> 2) + 4 * half;
      int* ob = out + (g0 + mw * 64 + i * 32 + row) * 256 + co0 + nw * 64 + l31;
#pragma unroll
      for (int j = 0; j < 2; ++j) {
        int v = acc[i][j][reg];
        ob[j * 32] = v;
        am = max(am, abs(v));
      }
    }
  }
  for (int off = 32; off; off >>= 1) am = max(am, __shfl_down(am, off, 64));
  if (lane == 0) reda[wave] = am;
  __syncthreads();
  if (t == 0) atomicMax(absmax_p, max(max(reda[0], reda[1]), max(reda[2], reda[3])));
}

// exact integer ceil(log2(v)); shift = max(bw-7,0); e_out = ea+eb+shift
__global__ void k_scale(const int* __restrict__ absmax_p,
                        const float* __restrict__ ea, const float* __restrict__ eb,
                        float* scale_out, float* e_out) {
  int v = *absmax_p;
  int p = 31 - __clz(v | 1);
  int bw = ((v & (v - 1)) == 0) ? p : p + 1;
  int shift = bw - 7; if (shift < 0) shift = 0;
  *scale_out = exp2f((float)(-shift));
  *e_out = *ea + *eb + (float)shift;
}

// quantize pixel-major acc [g][C] -> int8 q [g][C] + per-channel stats.
__global__ __launch_bounds__(256) void k_qstats_t(
    const int* __restrict__ acc, signed char* __restrict__ q,
    const float* __restrict__ scale_p, long long* sums,
    unsigned long long* sumsqs, int* mins, int* maxs, int Csh) {
  __shared__ int ls[256], lsq[256], lmn[256], lmx[256];
  int t = threadIdx.x;
  int C = 1 << Csh;
  size_t g0 = (size_t)blockIdx.x * 112;
  float scale = *scale_p;
  int c = t & (C - 1);
  int s = 0, sq = 0, mn = 127, mx = -128;
  for (int idx = t; idx < (112 << Csh); idx += 256) {
    int p = idx >> Csh;
    size_t a = ((g0 + p) << Csh) | (size_t)c;
    float r = rintf((float)acc[a] * scale);
    r = fminf(fmaxf(r, -128.f), 127.f);
    int qi = (int)r;
    q[a] = (signed char)qi;
    s += qi; sq += qi * qi; mn = min(mn, qi); mx = max(mx, qi);
  }
  ls[t] = s; lsq[t] = sq; lmn[t] = mn; lmx[t] = mx;
  __syncthreads();
  if (t < C) {
    for (int u = t + C; u < 256; u += C) {
      s += ls[u]; sq += lsq[u];
      mn = min(mn, lmn[u]); mx = max(mx, lmx[u]);
    }
    atomicAdd((unsigned long long*)&sums[c], (unsigned long long)(long long)s);
    atomicAdd(&sumsqs[c], (unsigned long long)(unsigned)sq);
    atomicMin(&mins[c], mn);
    atomicMax(&maxs[c], mx);
  }
}

// per-channel bn affine y = A*q + B; global rng from channel min/max extremes.
__global__ void k_bn(const long long* __restrict__ sums,
                     const unsigned long long* __restrict__ sumsqs,
                     const int* __restrict__ mins, const int* __restrict__ maxs,
                     const float* __restrict__ gamma, const float* __restrict__ beta,
                     const float* __restrict__ e_in,
                     float* A, float* Bc, float* s_out, float* e_out,
                     float* e_extra, int C) {
  __shared__ float red[4];
  int t = threadIdx.x;
  float e1 = *e_in;
  double meanq = (double)sums[t] / (double)NHW;
  double varq = (double)sumsqs[t] / (double)NHW - meanq * meanq;
  float se = exp2f(e1);
  float mean = (float)meanq * se;
  float var = (float)varq * se * se;
  float rsq = 1.0f / sqrtf(var + 1e-5f);
  float g = gamma[t], b = beta[t];
  float Av = g * se * rsq;
  float Bv = b - g * mean * rsq;
  A[t] = Av; Bc[t] = Bv;
  float cand = fmaxf(fabsf(Av * (float)mins[t] + Bv), fabsf(Av * (float)maxs[t] + Bv));
  for (int off = 32; off; off >>= 1) cand = fmaxf(cand, __shfl_down(cand, off, 64));
  int wave = t >> 6, lane = t & 63;
  if (lane == 0) red[wave] = cand;
  __syncthreads();
  if (t == 0) {
    float rng = red[0];
    for (int i = 1; i < C / 64; i++) rng = fmaxf(rng, red[i]);
    float bwv = ceilf(log2f(rng));
    *s_out = exp2f(7.0f - bwv);
    *e_out = bwv - 7.0f;
    if (e_extra) *e_extra = bwv - 7.0f;
  }
}

// q2t = relu(clip(round((A*q1+B)*s2))), pixel-major [g][128], 4 bytes/thread
__global__ __launch_bounds__(256) void k_q2t(
    const signed char* __restrict__ q1, signed char* __restrict__ q2,
    const Stats* __restrict__ st) {
  unsigned i = blockIdx.x * 256u + threadIdx.x;
  int v = ((const int*)q1)[i];
  int c0 = (i << 2) & 127;
  float s2 = st->s2;
  int outv = 0;
#pragma unroll
  for (int j = 0; j < 4; ++j) {
    int b = (signed char)(v >> (8 * j));
    float y = st->A1[c0 + j] * (float)b + st->B1c[c0 + j];
    float r = rintf(y * s2);
    r = fminf(fmaxf(r, -128.f), 127.f);
    r = fmaxf(r, 0.f);
    outv |= ((int)r & 0xff) << (8 * j);
  }
  ((int*)q2)[i] = outv;
}

// final: q3 [g][256] -> out NCHW float. Wave owns 64 consecutive pixels;
// writes are 256B-coalesced channel rows; reads are 4B int scatters (L2-hit).
__global__ __launch_bounds__(256) void k_out(
    const signed char* __restrict__ q3, const Stats* __restrict__ st,
    float* __restrict__ out) {
  int t = threadIdx.x, lane = t & 63, wave = t >> 6;
  int nb = blockIdx.x;                 // 1568 = 32n * 49
  int n = nb / 49, p0 = (nb - n * 49) * 64;
  const int* q3w = (const int*)(q3 + ((size_t)n * HW + p0) * 256);
  float sf = st->sf;
  float* ob = out + (size_t)n * C2 * HW + p0 + lane;
#pragma unroll
  for (int i = 0; i < 16; ++i) {
    int cg = wave * 16 + i;            // channel group (4 ch), wave-uniform
    int v = q3w[(size_t)lane * 64 + cg];
#pragma unroll
    for (int j = 0; j < 4; ++j) {
      int c = cg * 4 + j;
      float y = st->A2[c] * (float)((signed char)(v >> (8 * j))) + st->B2c[c];
      float r = rintf(y * sf);
      r = fminf(fmaxf(r, -128.f), 127.f);
      ob[(size_t)c * HW] = fmaxf(r, 0.f);
    }
  }
}

extern "C" void kernel_launch(void* const* d_in, const int* in_sizes, int n_in,
                              void* d_out, int out_size, void* d_ws, size_t ws_size,
                              hipStream_t stream) {
  const int* x = (const int*)d_in[0];
  const float* x_exp = (const float*)d_in[1];
  const float* wDW = (const float*)d_in[2];
  const float* wDW_exp = (const float*)d_in[3];
  const float* wPW = (const float*)d_in[4];
  const float* wPW_exp = (const float*)d_in[5];
  const float* gamma1 = (const float*)d_in[6];
  const float* beta1 = (const float*)d_in[7];
  const float* gamma2 = (const float*)d_in[8];
  const float* beta2 = (const float*)d_in[9];
  float* out = (float*)d_out;

  char* ws = (char*)d_ws;
  signed char* q2t = (signed char*)(ws + OFF_Q2T);
  signed char* q1 = (signed char*)(ws + OFF_Q1);
  signed char* wq2 = (signed char*)(ws + OFF_WQ2);
  int* acc1 = (int*)(ws + OFF_ACC1);
  signed char* xp = (signed char*)(ws + OFF_XP);
  int* acc2 = (int*)(ws + OFF_ACC2);
  signed char* q3 = (signed char*)(ws + OFF_Q3);
  signed char* wq1 = (signed char*)(ws + OFF_WQ1);
  Stats* st = (Stats*)(ws + OFF_STATS);

  hipMemsetAsync(xp, 0, XPSZ, stream);
  hipLaunchKernelGGL(k_init, dim3(1), dim3(256), 0, stream, st);
  hipLaunchKernelGGL(k_prep_x, dim3(56, 32), dim3(256), 0, stream, x, xp);
  hipLaunchKernelGGL(k_prep_w1, dim3(576), dim3(256), 0, stream, wDW, wq1);

  hipLaunchKernelGGL(k_conv1m, dim3(784), dim3(256), 0, stream,
                     xp, wq1, acc1, &st->absmax1);
  hipLaunchKernelGGL(k_scale, dim3(1), dim3(1), 0, stream,
                     &st->absmax1, x_exp, wDW_exp, &st->scale1, &st->e1);
  hipLaunchKernelGGL(k_qstats_t, dim3(896), dim3(256), 0, stream,
                     acc1, q1, &st->scale1, st->sum1, st->sumsq1, st->min1, st->max1, 7);
  hipLaunchKernelGGL(k_bn, dim3(1), dim3(C1), 0, stream,
                     st->sum1, st->sumsq1, st->min1, st->max1, gamma1, beta1,
                     &st->e1, st->A1, st->B1c, &st->s2, &st->e2, (float*)nullptr, C1);
  hipLaunchKernelGGL(k_q2t, dim3(12544), dim3(256), 0, stream, q1, q2t, st);

  hipLaunchKernelGGL(k_prep_w2, dim3(128), dim3(256), 0, stream, wPW, wq2);
  hipLaunchKernelGGL(k_conv2m, dim3(784, 2), dim3(256), 0, stream,
                     q2t, wq2, acc2, &st->absmax2);
  hipLaunchKernelGGL(k_scale, dim3(1), dim3(1), 0, stream,
                     &st->absmax2, &st->e2, wPW_exp, &st->scaleq2, &st->e3);
  hipLaunchKernelGGL(k_qstats_t, dim3(896), dim3(256), 0, stream,
                     acc2, q3, &st->scaleq2, st->sum2, st->sumsq2, st->min2, st->max2, 8);
  hipLaunchKernelGGL(k_bn, dim3(1), dim3(C2), 0, stream,
                     st->sum2, st->sumsq2, st->min2, st->max2, gamma2, beta2,
                     &st->e3, st->A2, st->B2c, &st->sf, &st->ef, out + N2, C2);
  hipLaunchKernelGGL(k_out, dim3(1568), dim3(256), 0, stream, q3, st, out);
}

// Round 4
// 353.334 us; speedup vs baseline: 3.4389x; 1.1294x over previous
//
#include <hip/hip_runtime.h>
#include <cstdint>
#include <cstddef>

#define Bsz 32
#define C1 128
#define C2 256
#define Hh 56
#define Wd 56
#define HW 3136                  // 56*56
#define NHW 100352               // 32*3136
#define N1 ((size_t)12845056)    // 32*128*3136
#define N2 ((size_t)25690112)    // 32*256*3136
#define XPSZ ((size_t)32 * 58 * 58 * 128)   // padded blocked int8 input

typedef int v4i __attribute__((ext_vector_type(4)));
typedef int v16i __attribute__((ext_vector_type(16)));

// ---- workspace layout (bytes) ----
// q2tt: [0, N1)              int8 [k16(8)][g][16]  (conv2 A, k-major)
// q1  : [N1, 2*N1)           int8 [g][128]   (dead after k_q2t; wq2t overlays)
// acc1: [2*N1, 6*N1)         int32 [g][128]
// xp2 : [6*N1, 6*N1+XPSZ)    int8 [n][hh(58)][k16(8)][ww(58)][16]
// acc2: [2*N1, 2*N1+4*N2)    int32 [g][256]  (overlays acc1+xp2)
// q3  : [2*N1+4*N2, +N2)     int8 [g][256]   (wq1t overlays start, dead first)
static constexpr size_t OFF_Q2T = 0;
static constexpr size_t OFF_Q1 = N1;
static constexpr size_t OFF_WQ2 = N1;            // overlays q1 (q1 dead first)
static constexpr size_t OFF_ACC1 = 2 * N1;
static constexpr size_t OFF_XP = 6 * N1;
static constexpr size_t OFF_ACC2 = 2 * N1;
static constexpr size_t OFF_Q3 = 2 * N1 + 4 * N2;
static constexpr size_t OFF_WQ1 = OFF_Q3;        // overlays q3 (wq1t dead before q3 written)
static constexpr size_t OFF_STATS = OFF_Q3 + N2;

struct Stats {
  int absmax1, absmax2, pad0, pad1;
  float scale1, e1, s2, e2;
  float scaleq2, e3, sf, ef;
  long long sum1[C1];
  unsigned long long sumsq1[C1];
  int min1[C1], max1[C1];
  float A1[C1], B1c[C1];
  long long sum2[C2];
  unsigned long long sumsq2[C2];
  int min2[C2], max2[C2];
  float A2[C2], B2c[C2];
};

__global__ void k_init(Stats* st) {
  int t = threadIdx.x;
  if (t == 0) { st->absmax1 = 0; st->absmax2 = 0; }
  for (int c = t; c < C1; c += 256) {
    st->sum1[c] = 0; st->sumsq1[c] = 0; st->min1[c] = 127; st->max1[c] = -128;
  }
  for (int c = t; c < C2; c += 256) {
    st->sum2[c] = 0; st->sumsq2[c] = 0; st->min2[c] = 127; st->max2[c] = -128;
  }
}

// x int32 NCHW -> xp2 int8 [n][hh][k16(8)][ww(58)][16], borders zeroed here.
// Block per (hh, n). LDS transpose; all global reads/writes coalesced.
__global__ __launch_bounds__(256) void k_prep_x2(
    const int* __restrict__ x, signed char* __restrict__ xp) {
  __shared__ signed char lds[56 * 132];
  int t = threadIdx.x;
  int hh = blockIdx.x;             // 0..57 padded row
  int n = blockIdx.y;
  int* xpw = (int*)(xp + ((size_t)n * 58 + hh) * 7424);
  if (hh == 0 || hh == 57) {
    for (int o = t; o < 1856; o += 256) xpw[o] = 0;
    return;
  }
  int h = hh - 1;
  const int* xb = x + (size_t)n * C1 * HW + h * 56;
  for (int idx = t; idx < 7168; idx += 256) {
    int c = idx / 56, w = idx - c * 56;
    lds[w * 132 + c] = (signed char)xb[(size_t)c * HW + w];
  }
  __syncthreads();
  for (int o = t; o < 1856; o += 256) {     // 8 kb * 58 ww * 4 words
    int kb = o / 232, r = o - kb * 232, ww = r >> 2, cw = r & 3;
    int val = (ww == 0 || ww == 57) ? 0
              : *(const int*)&lds[(ww - 1) * 132 + kb * 16 + cw * 4];
    xpw[o] = val;
  }
}

// wDW [co][ci][kh][kw] float -> wq1t int8 [k16(72)][co(128)][16], k=pos*128+ci
__global__ void k_prep_w1(const float* __restrict__ wDW, signed char* __restrict__ wq1t) {
  int idx = blockIdx.x * 256 + threadIdx.x;
  if (idx >= 128 * 1152) return;
  int co = idx / 1152, r = idx - co * 1152;
  int ci = r / 9, pos = r - ci * 9;
  int k = pos * 128 + ci;
  wq1t[(size_t)(k >> 4) * 2048 + co * 16 + (k & 15)] = (signed char)(int)wDW[idx];
}

// wPW [co][ci] float -> wq2t int8 [k16(8)][co(256)][16]
__global__ void k_prep_w2(const float* __restrict__ wPW, signed char* __restrict__ wq2t) {
  int i = blockIdx.x * 256 + threadIdx.x;   // 32768
  int co = i >> 7, ci = i & 127;
  wq2t[(size_t)(ci >> 4) * 4096 + co * 16 + (ci & 15)] = (signed char)(int)wPW[i];
}

// 3x3 conv 128->128 implicit GEMM, all loads coalesced via blocked layouts.
// Block: 128 pix x 128 co, 4 waves; wave: 64 pix x 64 co (2x2 MFMA subtiles).
__global__ __launch_bounds__(256, 3) void k_conv1m(
    const signed char* __restrict__ xp, const signed char* __restrict__ wq1t,
    int* __restrict__ out, int* __restrict__ absmax_p) {
  __shared__ int reda[4];
  int t = threadIdx.x, lane = t & 63, wave = t >> 6;
  int half = lane >> 5, l31 = lane & 31;
  int mw = wave & 1, nw = wave >> 1;
  size_t g0 = (size_t)blockIdx.x * 128;

  const signed char* ab[2];
#pragma unroll
  for (int i = 0; i < 2; ++i) {
    size_t gm = g0 + mw * 64 + i * 32 + l31;
    int n = (int)(gm / HW);
    int p = (int)(gm - (size_t)n * HW);
    int h = p / 56, w = p - h * 56;
    // row stride 7424 = 8*58*16, k16 stride 928 = 58*16
    ab[i] = xp + ((size_t)n * 58 + h) * 7424 + w * 16 + half * 928;
  }
  const signed char* bb[2];
#pragma unroll
  for (int j = 0; j < 2; ++j)
    bb[j] = wq1t + (size_t)(nw * 64 + j * 32 + l31) * 16 + half * 2048;

  v16i acc[2][2];
#pragma unroll
  for (int i = 0; i < 2; ++i)
#pragma unroll
    for (int j = 0; j < 2; ++j)
#pragma unroll
      for (int r = 0; r < 16; ++r) acc[i][j][r] = 0;

#pragma unroll
  for (int pos = 0; pos < 9; ++pos) {
    int kh = pos / 3, kw = pos - kh * 3;
    const signed char* a0 = ab[0] + kh * 7424 + kw * 16;
    const signed char* a1 = ab[1] + kh * 7424 + kw * 16;
    const signed char* b0 = bb[0] + pos * 16384;
    const signed char* b1 = bb[1] + pos * 16384;
#pragma unroll
    for (int kb = 0; kb < 8; kb += 2) {   // 32 k per step
      v4i af0 = *(const v4i*)(a0 + kb * 928);
      v4i af1 = *(const v4i*)(a1 + kb * 928);
      v4i bf0 = *(const v4i*)(b0 + kb * 2048);
      v4i bf1 = *(const v4i*)(b1 + kb * 2048);
      acc[0][0] = __builtin_amdgcn_mfma_i32_32x32x32_i8(af0, bf0, acc[0][0], 0, 0, 0);
      acc[0][1] = __builtin_amdgcn_mfma_i32_32x32x32_i8(af0, bf1, acc[0][1], 0, 0, 0);
      acc[1][0] = __builtin_amdgcn_mfma_i32_32x32x32_i8(af1, bf0, acc[1][0], 0, 0, 0);
      acc[1][1] = __builtin_amdgcn_mfma_i32_32x32x32_i8(af1, bf1, acc[1][1], 0, 0, 0);
    }
  }

  int am = 0;
#pragma unroll
  for (int i = 0; i < 2; ++i) {
#pragma unroll
    for (int reg = 0; reg < 16; ++reg) {
      int row = (reg & 3) + 8 * (reg >> 2) + 4 * half;
      int* ob = out + (g0 + mw * 64 + i * 32 + row) * 128 + nw * 64 + l31;
#pragma unroll
      for (int j = 0; j < 2; ++j) {
        int v = acc[i][j][reg];
        ob[j * 32] = v;
        am = max(am, abs(v));
      }
    }
  }
  for (int off = 32; off; off >>= 1) am = max(am, __shfl_down(am, off, 64));
  if (lane == 0) reda[wave] = am;
  __syncthreads();
  if (t == 0) atomicMax(absmax_p, max(max(reda[0], reda[1]), max(reda[2], reda[3])));
}

// 1x1 conv 128->256 GEMM; A from k-major q2tt (coalesced), B from wq2t.
__global__ __launch_bounds__(256, 3) void k_conv2m(
    const signed char* __restrict__ q2tt, const signed char* __restrict__ wq2t,
    int* __restrict__ out, int* __restrict__ absmax_p) {
  __shared__ int reda[4];
  int t = threadIdx.x, lane = t & 63, wave = t >> 6;
  int half = lane >> 5, l31 = lane & 31;
  int mw = wave & 1, nw = wave >> 1;
  size_t g0 = (size_t)blockIdx.x * 128;
  int co0 = blockIdx.y * 128;

  const signed char* ab[2];
#pragma unroll
  for (int i = 0; i < 2; ++i)
    ab[i] = q2tt + (g0 + mw * 64 + i * 32 + l31) * 16 + (size_t)half * NHW * 16;
  const signed char* bb[2];
#pragma unroll
  for (int j = 0; j < 2; ++j)
    bb[j] = wq2t + (size_t)(co0 + nw * 64 + j * 32 + l31) * 16 + half * 4096;

  v16i acc[2][2];
#pragma unroll
  for (int i = 0; i < 2; ++i)
#pragma unroll
    for (int j = 0; j < 2; ++j)
#pragma unroll
      for (int r = 0; r < 16; ++r) acc[i][j][r] = 0;

#pragma unroll
  for (int kb = 0; kb < 8; kb += 2) {
    v4i af0 = *(const v4i*)(ab[0] + (size_t)kb * (NHW * 16));
    v4i af1 = *(const v4i*)(ab[1] + (size_t)kb * (NHW * 16));
    v4i bf0 = *(const v4i*)(bb[0] + kb * 4096);
    v4i bf1 = *(const v4i*)(bb[1] + kb * 4096);
    acc[0][0] = __builtin_amdgcn_mfma_i32_32x32x32_i8(af0, bf0, acc[0][0], 0, 0, 0);
    acc[0][1] = __builtin_amdgcn_mfma_i32_32x32x32_i8(af0, bf1, acc[0][1], 0, 0, 0);
    acc[1][0] = __builtin_amdgcn_mfma_i32_32x32x32_i8(af1, bf0, acc[1][0], 0, 0, 0);
    acc[1][1] = __builtin_amdgcn_mfma_i32_32x32x32_i8(af1, bf1, acc[1][1], 0, 0, 0);
  }

  int am = 0;
#pragma unroll
  for (int i = 0; i < 2; ++i) {
#pragma unroll
    for (int reg = 0; reg < 16; ++reg) {
      int row = (reg & 3) + 8 * (reg >> 2) + 4 * half;
      int* ob = out + (g0 + mw * 64 + i * 32 + row) * 256 + co0 + nw * 64 + l31;
#pragma unroll
      for (int j = 0; j < 2; ++j) {
        int v = acc[i][j][reg];
        ob[j * 32] = v;
        am = max(am, abs(v));
      }
    }
  }
  for (int off = 32; off; off >>= 1) am = max(am, __shfl_down(am, off, 64));
  if (lane == 0) reda[wave] = am;
  __syncthreads();
  if (t == 0) atomicMax(absmax_p, max(max(reda[0], reda[1]), max(reda[2], reda[3])));
}

// exact integer ceil(log2(v)); shift = max(bw-7,0); e_out = ea+eb+shift
__global__ void k_scale(const int* __restrict__ absmax_p,
                        const float* __restrict__ ea, const float* __restrict__ eb,
                        float* scale_out, float* e_out) {
  int v = *absmax_p;
  int p = 31 - __clz(v | 1);
  int bw = ((v & (v - 1)) == 0) ? p : p + 1;
  int shift = bw - 7; if (shift < 0) shift = 0;
  *scale_out = exp2f((float)(-shift));
  *e_out = *ea + *eb + (float)shift;
}

// quantize pixel-major acc [g][C] -> int8 q [g][C] + per-channel stats.
__global__ __launch_bounds__(256) void k_qstats_t(
    const int* __restrict__ acc, signed char* __restrict__ q,
    const float* __restrict__ scale_p, long long* sums,
    unsigned long long* sumsqs, int* mins, int* maxs, int Csh) {
  __shared__ int ls[256], lsq[256], lmn[256], lmx[256];
  int t = threadIdx.x;
  int C = 1 << Csh;
  size_t g0 = (size_t)blockIdx.x * 112;
  float scale = *scale_p;
  int c = t & (C - 1);
  int s = 0, sq = 0, mn = 127, mx = -128;
  for (int idx = t; idx < (112 << Csh); idx += 256) {
    int p = idx >> Csh;
    size_t a = ((g0 + p) << Csh) | (size_t)c;
    float r = rintf((float)acc[a] * scale);
    r = fminf(fmaxf(r, -128.f), 127.f);
    int qi = (int)r;
    q[a] = (signed char)qi;
    s += qi; sq += qi * qi; mn = min(mn, qi); mx = max(mx, qi);
  }
  ls[t] = s; lsq[t] = sq; lmn[t] = mn; lmx[t] = mx;
  __syncthreads();
  if (t < C) {
    for (int u = t + C; u < 256; u += C) {
      s += ls[u]; sq += lsq[u];
      mn = min(mn, lmn[u]); mx = max(mx, lmx[u]);
    }
    atomicAdd((unsigned long long*)&sums[c], (unsigned long long)(long long)s);
    atomicAdd(&sumsqs[c], (unsigned long long)(unsigned)sq);
    atomicMin(&mins[c], mn);
    atomicMax(&maxs[c], mx);
  }
}

// per-channel bn affine y = A*q + B; global rng from channel min/max extremes.
__global__ void k_bn(const long long* __restrict__ sums,
                     const unsigned long long* __restrict__ sumsqs,
                     const int* __restrict__ mins, const int* __restrict__ maxs,
                     const float* __restrict__ gamma, const float* __restrict__ beta,
                     const float* __restrict__ e_in,
                     float* A, float* Bc, float* s_out, float* e_out,
                     float* e_extra, int C) {
  __shared__ float red[4];
  int t = threadIdx.x;
  float e1 = *e_in;
  double meanq = (double)sums[t] / (double)NHW;
  double varq = (double)sumsqs[t] / (double)NHW - meanq * meanq;
  float se = exp2f(e1);
  float mean = (float)meanq * se;
  float var = (float)varq * se * se;
  float rsq = 1.0f / sqrtf(var + 1e-5f);
  float g = gamma[t], b = beta[t];
  float Av = g * se * rsq;
  float Bv = b - g * mean * rsq;
  A[t] = Av; Bc[t] = Bv;
  float cand = fmaxf(fabsf(Av * (float)mins[t] + Bv), fabsf(Av * (float)maxs[t] + Bv));
  for (int off = 32; off; off >>= 1) cand = fmaxf(cand, __shfl_down(cand, off, 64));
  int wave = t >> 6, lane = t & 63;
  if (lane == 0) red[wave] = cand;
  __syncthreads();
  if (t == 0) {
    float rng = red[0];
    for (int i = 1; i < C / 64; i++) rng = fmaxf(rng, red[i]);
    float bwv = ceilf(log2f(rng));
    *s_out = exp2f(7.0f - bwv);
    *e_out = bwv - 7.0f;
    if (e_extra) *e_extra = bwv - 7.0f;
  }
}

// q2tt[k16][g][16] = relu(clip(round((A*q1+B)*s2))); LDS transpose; coalesced both sides.
__global__ __launch_bounds__(256) void k_q2t(
    const signed char* __restrict__ q1, signed char* __restrict__ q2tt,
    const Stats* __restrict__ st) {
  __shared__ signed char lds[64 * 144];
  int t = threadIdx.x;
  size_t g0 = (size_t)blockIdx.x * 64;
  const int* q1w = (const int*)(q1 + g0 * 128);
  float s2 = st->s2;
#pragma unroll
  for (int it = 0; it < 8; ++it) {
    int o = it * 256 + t;
    int v = q1w[o];
    int pix = o >> 5, c0 = (o & 31) * 4;
    int outv = 0;
#pragma unroll
    for (int j = 0; j < 4; ++j) {
      int b = (signed char)(v >> (8 * j));
      float y = st->A1[c0 + j] * (float)b + st->B1c[c0 + j];
      float r = rintf(y * s2);
      r = fminf(fmaxf(r, -128.f), 127.f);
      r = fmaxf(r, 0.f);
      outv |= ((int)r & 0xff) << (8 * j);
    }
    *(int*)&lds[pix * 144 + c0] = outv;
  }
  __syncthreads();
  int* ow = (int*)q2tt;
#pragma unroll
  for (int it = 0; it < 8; ++it) {      // it == k16
    int r = t, gl = r >> 2, cw = r & 3;
    int val = *(const int*)&lds[gl * 144 + it * 16 + cw * 4];
    ow[((size_t)it * NHW + g0 + gl) * 4 + cw] = val;
  }
}

// final: q3 [g][256] -> out NCHW float. Writes 256B-coalesced channel rows.
__global__ __launch_bounds__(256) void k_out(
    const signed char* __restrict__ q3, const Stats* __restrict__ st,
    float* __restrict__ out) {
  int t = threadIdx.x, lane = t & 63, wave = t >> 6;
  int nb = blockIdx.x;                 // 1568 = 32n * 49
  int n = nb / 49, p0 = (nb - n * 49) * 64;
  const int* q3w = (const int*)(q3 + ((size_t)n * HW + p0) * 256);
  float sf = st->sf;
  float* ob = out + (size_t)n * C2 * HW + p0 + lane;
#pragma unroll
  for (int i = 0; i < 16; ++i) {
    int cg = wave * 16 + i;            // channel group (4 ch), wave-uniform
    int v = q3w[(size_t)lane * 64 + cg];
#pragma unroll
    for (int j = 0; j < 4; ++j) {
      int c = cg * 4 + j;
      float y = st->A2[c] * (float)((signed char)(v >> (8 * j))) + st->B2c[c];
      float r = rintf(y * sf);
      r = fminf(fmaxf(r, -128.f), 127.f);
      ob[(size_t)c * HW] = fmaxf(r, 0.f);
    }
  }
}

extern "C" void kernel_launch(void* const* d_in, const int* in_sizes, int n_in,
                              void* d_out, int out_size, void* d_ws, size_t ws_size,
                              hipStream_t stream) {
  const int* x = (const int*)d_in[0];
  const float* x_exp = (const float*)d_in[1];
  const float* wDW = (const float*)d_in[2];
  const float* wDW_exp = (const float*)d_in[3];
  const float* wPW = (const float*)d_in[4];
  const float* wPW_exp = (const float*)d_in[5];
  const float* gamma1 = (const float*)d_in[6];
  const float* beta1 = (const float*)d_in[7];
  const float* gamma2 = (const float*)d_in[8];
  const float* beta2 = (const float*)d_in[9];
  float* out = (float*)d_out;

  char* ws = (char*)d_ws;
  signed char* q2tt = (signed char*)(ws + OFF_Q2T);
  signed char* q1 = (signed char*)(ws + OFF_Q1);
  signed char* wq2t = (signed char*)(ws + OFF_WQ2);
  int* acc1 = (int*)(ws + OFF_ACC1);
  signed char* xp2 = (signed char*)(ws + OFF_XP);
  int* acc2 = (int*)(ws + OFF_ACC2);
  signed char* q3 = (signed char*)(ws + OFF_Q3);
  signed char* wq1t = (signed char*)(ws + OFF_WQ1);
  Stats* st = (Stats*)(ws + OFF_STATS);

  hipLaunchKernelGGL(k_init, dim3(1), dim3(256), 0, stream, st);
  hipLaunchKernelGGL(k_prep_x2, dim3(58, 32), dim3(256), 0, stream, x, xp2);
  hipLaunchKernelGGL(k_prep_w1, dim3(576), dim3(256), 0, stream, wDW, wq1t);

  hipLaunchKernelGGL(k_conv1m, dim3(784), dim3(256), 0, stream,
                     xp2, wq1t, acc1, &st->absmax1);
  hipLaunchKernelGGL(k_scale, dim3(1), dim3(1), 0, stream,
                     &st->absmax1, x_exp, wDW_exp, &st->scale1, &st->e1);
  hipLaunchKernelGGL(k_qstats_t, dim3(896), dim3(256), 0, stream,
                     acc1, q1, &st->scale1, st->sum1, st->sumsq1, st->min1, st->max1, 7);
  hipLaunchKernelGGL(k_bn, dim3(1), dim3(C1), 0, stream,
                     st->sum1, st->sumsq1, st->min1, st->max1, gamma1, beta1,
                     &st->e1, st->A1, st->B1c, &st->s2, &st->e2, (float*)nullptr, C1);
  hipLaunchKernelGGL(k_q2t, dim3(1568), dim3(256), 0, stream, q1, q2tt, st);

  hipLaunchKernelGGL(k_prep_w2, dim3(128), dim3(256), 0, stream, wPW, wq2t);
  hipLaunchKernelGGL(k_conv2m, dim3(784, 2), dim3(256), 0, stream,
                     q2tt, wq2t, acc2, &st->absmax2);
  hipLaunchKernelGGL(k_scale, dim3(1), dim3(1), 0, stream,
                     &st->absmax2, &st->e2, wPW_exp, &st->scaleq2, &st->e3);
  hipLaunchKernelGGL(k_qstats_t, dim3(896), dim3(256), 0, stream,
                     acc2, q3, &st->scaleq2, st->sum2, st->sumsq2, st->min2, st->max2, 8);
  hipLaunchKernelGGL(k_bn, dim3(1), dim3(C2), 0, stream,
                     st->sum2, st->sumsq2, st->min2, st->max2, gamma2, beta2,
                     &st->e3, st->A2, st->B2c, &st->sf, &st->ef, out + N2, C2);
  hipLaunchKernelGGL(k_out, dim3(1568), dim3(256), 0, stream, q3, st, out);
}

// Round 6
// 312.851 us; speedup vs baseline: 3.8839x; 1.1294x over previous
//
#include <hip/hip_runtime.h>
#include <cstdint>
#include <cstddef>

#define C1 128
#define C2 256
#define Hh 56
#define Wd 56
#define HW 3136                  // 56*56
#define NHW 100352               // 32*3136
#define N1 ((size_t)12845056)    // 32*128*3136
#define N2 ((size_t)25690112)    // 32*256*3136
#define XPSZ ((size_t)13778944)  // 32*58*58*128

typedef int v4i __attribute__((ext_vector_type(4)));
typedef int v16i __attribute__((ext_vector_type(16)));

// ---- workspace layout (bytes) ----
static constexpr size_t OFF_XP = 0;
static constexpr size_t OFF_Q1 = XPSZ;
static constexpr size_t OFF_Q3 = OFF_Q1 + N1;
static constexpr size_t OFF_WQ1 = OFF_Q3 + N2;
static constexpr size_t OFF_WQ2 = OFF_WQ1 + 147456;
static constexpr size_t OFF_STATS = OFF_WQ2 + 32768;

struct Stats {
  int absmax1, absmax2, pad0, pad1;
  float scale1, e1, s2, e2;
  float scaleq2, e3, sf, ef;
  long long sum1[C1];
  unsigned long long sumsq1[C1];
  int min1[C1], max1[C1];
  float A1[C1], B1c[C1];
  long long sum2[C2];
  unsigned long long sumsq2[C2];
  int min2[C2], max2[C2];
  float A2[C2], B2c[C2];
};

__global__ void k_init(Stats* st) {
  int t = threadIdx.x;
  if (t == 0) { st->absmax1 = 0; st->absmax2 = 0; }
  for (int c = t; c < C1; c += 256) {
    st->sum1[c] = 0; st->sumsq1[c] = 0; st->min1[c] = 127; st->max1[c] = -128;
  }
  for (int c = t; c < C2; c += 256) {
    st->sum2[c] = 0; st->sumsq2[c] = 0; st->min2[c] = 127; st->max2[c] = -128;
  }
}

// x int32 NCHW -> xp int8 [n][hh(58)][k16(8)][ww(58)][16], borders zeroed.
__global__ __launch_bounds__(256) void k_prep_x2(
    const int* __restrict__ x, signed char* __restrict__ xp) {
  __shared__ signed char lds[56 * 132];
  int t = threadIdx.x;
  int hh = blockIdx.x;             // 0..57
  int n = blockIdx.y;
  int* xpw = (int*)(xp + ((size_t)n * 58 + hh) * 7424);
  if (hh == 0 || hh == 57) {
    for (int o = t; o < 1856; o += 256) xpw[o] = 0;
    return;
  }
  int h = hh - 1;
  const int* xb = x + (size_t)n * C1 * HW + h * 56;
  for (int idx = t; idx < 7168; idx += 256) {
    int c = idx / 56, w = idx - c * 56;
    lds[w * 132 + c] = (signed char)xb[(size_t)c * HW + w];
  }
  __syncthreads();
  for (int o = t; o < 1856; o += 256) {
    int kb = o / 232, r = o - kb * 232, ww = r >> 2, cw = r & 3;
    int val = (ww == 0 || ww == 57) ? 0
              : *(const int*)&lds[(ww - 1) * 132 + kb * 16 + cw * 4];
    xpw[o] = val;
  }
}

// wDW [co][ci][3][3] float -> wq1t int8 [k16(72)][co(128)][16], k=pos*128+ci
__global__ void k_prep_w1(const float* __restrict__ wDW, signed char* __restrict__ wq1t) {
  int idx = blockIdx.x * 256 + threadIdx.x;
  if (idx >= 128 * 1152) return;
  int co = idx / 1152, r = idx - co * 1152;
  int ci = r / 9, pos = r - ci * 9;
  int k = pos * 128 + ci;
  wq1t[(size_t)(k >> 4) * 2048 + co * 16 + (k & 15)] = (signed char)(int)wDW[idx];
}

// wPW [co][ci] float -> wq2t int8 [k16(8)][co(256)][16]
__global__ void k_prep_w2(const float* __restrict__ wPW, signed char* __restrict__ wq2t) {
  int i = blockIdx.x * 256 + threadIdx.x;   // 32768
  int co = i >> 7, ci = i & 127;
  wq2t[(size_t)(ci >> 4) * 4096 + co * 16 + (ci & 15)] = (signed char)(int)wPW[i];
}

// exact integer ceil(log2(v)); shift = max(bw-7,0); e_out = ea+eb+shift
__global__ void k_scale(const int* __restrict__ absmax_p,
                        const float* __restrict__ ea, const float* __restrict__ eb,
                        float* scale_out, float* e_out) {
  int v = *absmax_p;
  int p = 31 - __clz(v | 1);
  int bw = ((v & (v - 1)) == 0) ? p : p + 1;
  int shift = bw - 7; if (shift < 0) shift = 0;
  *scale_out = exp2f((float)(-shift));
  *e_out = *ea + *eb + (float)shift;
}

__device__ inline v4i ld16_lds(const signed char* p) {
  const int2* q = (const int2*)p;          // 8-byte aligned (stride 136)
  int2 lo = q[0], hi = q[1];
  v4i r; r[0] = lo.x; r[1] = lo.y; r[2] = hi.x; r[3] = hi.y;
  return r;
}

// 3x3 conv 128->128, block = 256 pixels x 128 co, acc in registers.
// STORE=0: absmax1 only. STORE=1: quantize -> q1 [g][128] + per-channel stats.
template <int STORE>
__global__ __launch_bounds__(256, 2) void k_conv1t(
    const signed char* __restrict__ xp, const signed char* __restrict__ wq1t,
    signed char* __restrict__ q1, Stats* st) {
  __shared__ int qti[256 * 34];            // 256 pixels x 136B (stride 34 ints)
  __shared__ int psum[C1], psq[C1], pmn[C1], pmx[C1];
  __shared__ int reda[4];
  signed char* qt = (signed char*)qti;

  int t = threadIdx.x, lane = t & 63, wave = t >> 6;
  int half = lane >> 5, l31 = lane & 31;
  size_t g0 = (size_t)blockIdx.x * 256;

  const signed char* ab[2];
#pragma unroll
  for (int i = 0; i < 2; ++i) {
    size_t gm = g0 + wave * 64 + i * 32 + l31;
    int n = (int)(gm / HW);
    int p = (int)(gm - (size_t)n * HW);
    int h = p / 56, w = p - h * 56;
    ab[i] = xp + ((size_t)n * 58 + h) * 7424 + w * 16 + half * 928;
  }
  const signed char* bb[4];
#pragma unroll
  for (int j = 0; j < 4; ++j)
    bb[j] = wq1t + (size_t)(j * 32 + l31) * 16 + half * 2048;

  v16i a1[2][4];
#pragma unroll
  for (int i = 0; i < 2; ++i)
#pragma unroll
    for (int j = 0; j < 4; ++j)
#pragma unroll
      for (int r = 0; r < 16; ++r) a1[i][j][r] = 0;

#pragma unroll
  for (int pos = 0; pos < 9; ++pos) {
    int kh = pos / 3, kw = pos - kh * 3;
    const signed char* a0p = ab[0] + kh * 7424 + kw * 16;
    const signed char* a1p = ab[1] + kh * 7424 + kw * 16;
#pragma unroll
    for (int kb = 0; kb < 8; kb += 2) {
      v4i af0 = *(const v4i*)(a0p + kb * 928);
      v4i af1 = *(const v4i*)(a1p + kb * 928);
      v4i bf[4];
#pragma unroll
      for (int j = 0; j < 4; ++j)
        bf[j] = *(const v4i*)(bb[j] + pos * 16384 + kb * 2048);
#pragma unroll
      for (int j = 0; j < 4; ++j) {
        a1[0][j] = __builtin_amdgcn_mfma_i32_32x32x32_i8(af0, bf[j], a1[0][j], 0, 0, 0);
        a1[1][j] = __builtin_amdgcn_mfma_i32_32x32x32_i8(af1, bf[j], a1[1][j], 0, 0, 0);
      }
    }
  }

  if (STORE == 0) {
    int am = 0;
#pragma unroll
    for (int i = 0; i < 2; ++i)
#pragma unroll
      for (int j = 0; j < 4; ++j)
#pragma unroll
        for (int r = 0; r < 16; ++r) am = max(am, abs(a1[i][j][r]));
    for (int off = 32; off; off >>= 1) am = max(am, __shfl_down(am, off, 64));
    if (lane == 0) reda[wave] = am;
    __syncthreads();
    if (t == 0)
      atomicMax(&st->absmax1, max(max(reda[0], reda[1]), max(reda[2], reda[3])));
  } else {
    if (t < C1) { psum[t] = 0; psq[t] = 0; pmn[t] = 127; pmx[t] = -128; }
    __syncthreads();
    float scale1 = st->scale1;
#pragma unroll
    for (int j = 0; j < 4; ++j) {
      int sj = 0, sqj = 0, mnj = 127, mxj = -128;
      int c = j * 32 + l31;
#pragma unroll
      for (int i = 0; i < 2; ++i)
#pragma unroll
        for (int reg = 0; reg < 16; ++reg) {
          int row = (reg & 3) + 8 * (reg >> 2) + 4 * half;
          int pix = wave * 64 + i * 32 + row;
          float r = rintf((float)a1[i][j][reg] * scale1);
          r = fminf(fmaxf(r, -128.f), 127.f);
          int qi = (int)r;
          qt[pix * 136 + c] = (signed char)qi;
          sj += qi; sqj += qi * qi; mnj = min(mnj, qi); mxj = max(mxj, qi);
        }
      sj += __shfl_down(sj, 32, 64);
      sqj += __shfl_down(sqj, 32, 64);
      mnj = min(mnj, __shfl_down(mnj, 32, 64));
      mxj = max(mxj, __shfl_down(mxj, 32, 64));
      if (half == 0) {
        atomicAdd(&psum[c], sj); atomicAdd(&psq[c], sqj);
        atomicMin(&pmn[c], mnj); atomicMax(&pmx[c], mxj);
      }
    }
    __syncthreads();
    if (t < C1) {
      atomicAdd((unsigned long long*)&st->sum1[t],
                (unsigned long long)(long long)psum[t]);
      atomicAdd(&st->sumsq1[t], (unsigned long long)(unsigned)psq[t]);
      atomicMin(&st->min1[t], pmn[t]);
      atomicMax(&st->max1[t], pmx[t]);
    }
    // coalesced LDS -> global copy
    int* q1w = (int*)(q1 + g0 * 128);
    for (int idx = t; idx < 8192; idx += 256) {
      int pix = idx >> 5, c4 = idx & 31;
      q1w[idx] = qti[pix * 34 + c4];
    }
  }
}

// 1x1 conv 128->256, block = 256 pixels x 256 co. Rebuilds q2 from q1 via bn1
// affine (LDS tile), then MFMA. STORE=0: absmax2. STORE=1: q3 + stats.
template <int STORE>
__global__ __launch_bounds__(256, 2) void k_conv2t(
    const signed char* __restrict__ q1, const signed char* __restrict__ wq2t,
    signed char* __restrict__ q3, Stats* st) {
  __shared__ int qti[256 * 34];
  __shared__ int psum[C2], psq[C2], pmn[C2], pmx[C2];
  __shared__ int reda[4];
  signed char* qt = (signed char*)qti;

  int t = threadIdx.x, lane = t & 63, wave = t >> 6;
  int half = lane >> 5, l31 = lane & 31;
  size_t g0 = (size_t)blockIdx.x * 256;

  if (STORE) {
    psum[t] = 0; psq[t] = 0; pmn[t] = 127; pmx[t] = -128;
  }
  // bn1 coefficients for this thread's fixed 4 channels
  int c4 = t & 31;
  float Av[4], Bv[4];
#pragma unroll
  for (int jj = 0; jj < 4; ++jj) {
    Av[jj] = st->A1[c4 * 4 + jj];
    Bv[jj] = st->B1c[c4 * 4 + jj];
  }
  float s2 = st->s2;
  // load q1 tile coalesced, transform q1 -> q2, write LDS
  const int* q1w = (const int*)(q1 + g0 * 128);
#pragma unroll
  for (int k = 0; k < 32; ++k) {
    int idx = k * 256 + t;
    int v = q1w[idx];
    int pix = idx >> 5;
    int outv = 0;
#pragma unroll
    for (int jj = 0; jj < 4; ++jj) {
      int b = (signed char)(v >> (8 * jj));
      float y = Av[jj] * (float)b + Bv[jj];
      float r = rintf(y * s2);
      r = fminf(fmaxf(r, -128.f), 127.f);
      r = fmaxf(r, 0.f);
      outv |= ((int)r & 0xff) << (8 * jj);
    }
    qti[pix * 34 + c4] = outv;
  }
  __syncthreads();

  float scale2 = STORE ? st->scaleq2 : 0.f;
  int am2 = 0;
#pragma unroll
  for (int ch = 0; ch < 2; ++ch) {
    v16i a2[2][4];
#pragma unroll
    for (int i = 0; i < 2; ++i)
#pragma unroll
      for (int j = 0; j < 4; ++j)
#pragma unroll
        for (int r = 0; r < 16; ++r) a2[i][j][r] = 0;
#pragma unroll
    for (int ks = 0; ks < 4; ++ks) {
      v4i af[2];
#pragma unroll
      for (int i = 0; i < 2; ++i)
        af[i] = ld16_lds(&qt[(wave * 64 + i * 32 + l31) * 136 + half * 16 + ks * 32]);
      v4i bf[4];
#pragma unroll
      for (int j = 0; j < 4; ++j)
        bf[j] = *(const v4i*)(wq2t + (size_t)(ks * 2 + half) * 4096 +
                              (ch * 128 + j * 32 + l31) * 16);
#pragma unroll
      for (int j = 0; j < 4; ++j) {
        a2[0][j] = __builtin_amdgcn_mfma_i32_32x32x32_i8(af[0], bf[j], a2[0][j], 0, 0, 0);
        a2[1][j] = __builtin_amdgcn_mfma_i32_32x32x32_i8(af[1], bf[j], a2[1][j], 0, 0, 0);
      }
    }
    if (STORE == 0) {
#pragma unroll
      for (int i = 0; i < 2; ++i)
#pragma unroll
        for (int j = 0; j < 4; ++j)
#pragma unroll
          for (int r = 0; r < 16; ++r) am2 = max(am2, abs(a2[i][j][r]));
    } else {
#pragma unroll
      for (int j = 0; j < 4; ++j) {
        int sj = 0, sqj = 0, mnj = 127, mxj = -128;
        int c = ch * 128 + j * 32 + l31;
#pragma unroll
        for (int i = 0; i < 2; ++i)
#pragma unroll
          for (int reg = 0; reg < 16; ++reg) {
            int row = (reg & 3) + 8 * (reg >> 2) + 4 * half;
            size_t g = g0 + wave * 64 + i * 32 + row;
            float r = rintf((float)a2[i][j][reg] * scale2);
            r = fminf(fmaxf(r, -128.f), 127.f);
            int qi = (int)r;
            q3[g * 256 + c] = (signed char)qi;
            sj += qi; sqj += qi * qi; mnj = min(mnj, qi); mxj = max(mxj, qi);
          }
        sj += __shfl_down(sj, 32, 64);
        sqj += __shfl_down(sqj, 32, 64);
        mnj = min(mnj, __shfl_down(mnj, 32, 64));
        mxj = max(mxj, __shfl_down(mxj, 32, 64));
        if (half == 0) {
          atomicAdd(&psum[c], sj); atomicAdd(&psq[c], sqj);
          atomicMin(&pmn[c], mnj); atomicMax(&pmx[c], mxj);
        }
      }
    }
  }
  if (STORE == 0) {
    for (int off = 32; off; off >>= 1) am2 = max(am2, __shfl_down(am2, off, 64));
    if (lane == 0) reda[wave] = am2;
    __syncthreads();
    if (t == 0)
      atomicMax(&st->absmax2, max(max(reda[0], reda[1]), max(reda[2], reda[3])));
  } else {
    __syncthreads();
    atomicAdd((unsigned long long*)&st->sum2[t],
              (unsigned long long)(long long)psum[t]);
    atomicAdd(&st->sumsq2[t], (unsigned long long)(unsigned)psq[t]);
    atomicMin(&st->min2[t], pmn[t]);
    atomicMax(&st->max2[t], pmx[t]);
  }
}

// per-channel bn affine y = A*q + B; global rng from channel min/max extremes.
__global__ void k_bn(const long long* __restrict__ sums,
                     const unsigned long long* __restrict__ sumsqs,
                     const int* __restrict__ mins, const int* __restrict__ maxs,
                     const float* __restrict__ gamma, const float* __restrict__ beta,
                     const float* __restrict__ e_in,
                     float* A, float* Bc, float* s_out, float* e_out,
                     float* e_extra, int C) {
  __shared__ float red[4];
  int t = threadIdx.x;
  float e1 = *e_in;
  double meanq = (double)sums[t] / (double)NHW;
  double varq = (double)sumsqs[t] / (double)NHW - meanq * meanq;
  float se = exp2f(e1);
  float mean = (float)meanq * se;
  float var = (float)varq * se * se;
  float rsq = 1.0f / sqrtf(var + 1e-5f);
  float g = gamma[t], b = beta[t];
  float Avv = g * se * rsq;
  float Bvv = b - g * mean * rsq;
  A[t] = Avv; Bc[t] = Bvv;
  float cand = fmaxf(fabsf(Avv * (float)mins[t] + Bvv), fabsf(Avv * (float)maxs[t] + Bvv));
  for (int off = 32; off; off >>= 1) cand = fmaxf(cand, __shfl_down(cand, off, 64));
  int wave = t >> 6, lane = t & 63;
  if (lane == 0) red[wave] = cand;
  __syncthreads();
  if (t == 0) {
    float rng = red[0];
    for (int i = 1; i < C / 64; i++) rng = fmaxf(rng, red[i]);
    float bwv = ceilf(log2f(rng));
    *s_out = exp2f(7.0f - bwv);
    *e_out = bwv - 7.0f;
    if (e_extra) *e_extra = bwv - 7.0f;
  }
}

// final: q3 [g][256] -> out NCHW float. Writes 256B-coalesced channel rows.
__global__ __launch_bounds__(256) void k_out(
    const signed char* __restrict__ q3, const Stats* __restrict__ st,
    float* __restrict__ out) {
  int t = threadIdx.x, lane = t & 63, wave = t >> 6;
  int nb = blockIdx.x;                 // 1568 = 32n * 49
  int n = nb / 49, p0 = (nb - n * 49) * 64;
  const int* q3w = (const int*)(q3 + ((size_t)n * HW + p0) * 256);
  float sf = st->sf;
  float* ob = out + (size_t)n * C2 * HW + p0 + lane;
#pragma unroll
  for (int i = 0; i < 16; ++i) {
    int cg2 = wave * 16 + i;
    int v = q3w[(size_t)lane * 64 + cg2];
#pragma unroll
    for (int j = 0; j < 4; ++j) {
      int c = cg2 * 4 + j;
      float y = st->A2[c] * (float)((signed char)(v >> (8 * j))) + st->B2c[c];
      float r = rintf(y * sf);
      r = fminf(fmaxf(r, -128.f), 127.f);
      ob[(size_t)c * HW] = fmaxf(r, 0.f);
    }
  }
}

extern "C" void kernel_launch(void* const* d_in, const int* in_sizes, int n_in,
                              void* d_out, int out_size, void* d_ws, size_t ws_size,
                              hipStream_t stream) {
  const int* x = (const int*)d_in[0];
  const float* x_exp = (const float*)d_in[1];
  const float* wDW = (const float*)d_in[2];
  const float* wDW_exp = (const float*)d_in[3];
  const float* wPW = (const float*)d_in[4];
  const float* wPW_exp = (const float*)d_in[5];
  const float* gamma1 = (const float*)d_in[6];
  const float* beta1 = (const float*)d_in[7];
  const float* gamma2 = (const float*)d_in[8];
  const float* beta2 = (const float*)d_in[9];
  float* out = (float*)d_out;

  char* ws = (char*)d_ws;
  signed char* xp2 = (signed char*)(ws + OFF_XP);
  signed char* q1 = (signed char*)(ws + OFF_Q1);
  signed char* q3 = (signed char*)(ws + OFF_Q3);
  signed char* wq1t = (signed char*)(ws + OFF_WQ1);
  signed char* wq2t = (signed char*)(ws + OFF_WQ2);
  Stats* st = (Stats*)(ws + OFF_STATS);

  hipLaunchKernelGGL(k_init, dim3(1), dim3(256), 0, stream, st);
  hipLaunchKernelGGL(k_prep_x2, dim3(58, 32), dim3(256), 0, stream, x, xp2);
  hipLaunchKernelGGL(k_prep_w1, dim3(576), dim3(256), 0, stream, wDW, wq1t);
  hipLaunchKernelGGL(k_prep_w2, dim3(128), dim3(256), 0, stream, wPW, wq2t);

  hipLaunchKernelGGL(k_conv1t<0>, dim3(392), dim3(256), 0, stream,
                     xp2, wq1t, q1, st);
  hipLaunchKernelGGL(k_scale, dim3(1), dim3(1), 0, stream,
                     &st->absmax1, x_exp, wDW_exp, &st->scale1, &st->e1);
  hipLaunchKernelGGL(k_conv1t<1>, dim3(392), dim3(256), 0, stream,
                     xp2, wq1t, q1, st);
  hipLaunchKernelGGL(k_bn, dim3(1), dim3(C1), 0, stream,
                     st->sum1, st->sumsq1, st->min1, st->max1, gamma1, beta1,
                     &st->e1, st->A1, st->B1c, &st->s2, &st->e2, (float*)nullptr, C1);

  hipLaunchKernelGGL(k_conv2t<0>, dim3(392), dim3(256), 0, stream,
                     q1, wq2t, q3, st);
  hipLaunchKernelGGL(k_scale, dim3(1), dim3(1), 0, stream,
                     &st->absmax2, &st->e2, wPW_exp, &st->scaleq2, &st->e3);
  hipLaunchKernelGGL(k_conv2t<1>, dim3(392), dim3(256), 0, stream,
                     q1, wq2t, q3, st);
  hipLaunchKernelGGL(k_bn, dim3(1), dim3(C2), 0, stream,
                     st->sum2, st->sumsq2, st->min2, st->max2, gamma2, beta2,
                     &st->e3, st->A2, st->B2c, &st->sf, &st->ef, out + N2, C2);
  hipLaunchKernelGGL(k_out, dim3(1568), dim3(256), 0, stream, q3, st, out);
}